// Round 1
// baseline (292.364 us; speedup 1.0000x reference)
//
#include <hip/hip_runtime.h>

// AVWGCN: B=32, N=2048, C=64, O=64, K=3, D=16
// R14 changes vs R13 (gemm_bt 49us at MfmaUtil 29% / VALU 17% / HBM 28% -> stall-bound,
// 2-phase 128^2 structure at its ~700TF ceiling):
//  - gemm_bt256: 256^2 tile, BK=64, 512 thr (8 waves, 2Mx4N), dbuf 128KB LDS,
//    global_load_lds staging (pre-swizzled source, linear dest, XOR-swizzled reads),
//    4 quadrant-phases per K-tile with raw s_barrier + lgkmcnt(0) + setprio(1) around
//    each 16-MFMA cluster; next tile's 8 loads issued at phase 0 into the free buffer,
//    single vmcnt(0) at phase 3 (counted-wait analog: ~3 phases of cover).
//    Grid 8x8x4 = 256 blocks = exactly 1 block/CU (no dispatch tail) + bijective
//    XCD swizzle for L2 panel locality.
// Rest identical to R13 (fused preamble/mid, Wn-mode gconv, 8 dispatches).

typedef unsigned short u16;
typedef float f32x4 __attribute__((ext_vector_type(4)));
typedef __bf16 bf16x8 __attribute__((ext_vector_type(8)));
typedef unsigned short u16x8 __attribute__((ext_vector_type(8)));

#define PSTRIDE ((size_t)2048 * 2048)

__device__ __forceinline__ u16 f2bf(float f) {
    unsigned u = __float_as_uint(f);
    u += 0x7FFFu + ((u >> 16) & 1u);   // RNE
    return (u16)(u >> 16);
}
__device__ __forceinline__ float bf2f(u16 h) {
    return __uint_as_float((unsigned)h << 16);
}
__device__ __forceinline__ void gl_lds16(const void* g, void* l) {
    __builtin_amdgcn_global_load_lds(
        (const __attribute__((address_space(1))) unsigned*)g,
        (__attribute__((address_space(3))) unsigned*)l, 16, 0, 0);
}

// ---------------------------------------------------------------- preamble (fused)
__global__ __launch_bounds__(256)
void preamble(const float* __restrict__ E, const float* __restrict__ adj,
              const float* __restrict__ saw, const float* __restrict__ x,
              const float* __restrict__ Wp, const float* __restrict__ bp,
              float* __restrict__ zf, u16* __restrict__ Acat,
              u16* __restrict__ sawb, u16* __restrict__ xtT,
              u16* __restrict__ Wpb, float* __restrict__ Wpbf,
              float* __restrict__ bias, u16* __restrict__ xn, int mode) {
    __shared__ u16 t[64][65];
    __shared__ float Bp[1024];
    const int bid = blockIdx.x, tid = threadIdx.x;

    if (bid < 256) {
        const int c0 = (bid & 31) * 64, r0 = (bid >> 5) * 256;
        const int r = r0 + tid;
        const float4* Er = (const float4*)(E + (size_t)r * 16);
        float4 e0 = Er[0], e1 = Er[1], e2 = Er[2], e3 = Er[3];
        *(float4*)(Bp + tid * 4) = *(const float4*)(E + (size_t)c0 * 16 + tid * 4);
        __syncthreads();
        float* zr = zf + (size_t)r * 2048 + c0;
#pragma unroll
        for (int cc = 0; cc < 4; ++cc) {
            float acc[16];
#pragma unroll
            for (int c = 0; c < 16; ++c) {
                const float* bp2 = Bp + (cc * 16 + c) * 16;
                float s = 0.f;
                s = fmaf(e0.x, bp2[0], s);  s = fmaf(e0.y, bp2[1], s);
                s = fmaf(e0.z, bp2[2], s);  s = fmaf(e0.w, bp2[3], s);
                s = fmaf(e1.x, bp2[4], s);  s = fmaf(e1.y, bp2[5], s);
                s = fmaf(e1.z, bp2[6], s);  s = fmaf(e1.w, bp2[7], s);
                s = fmaf(e2.x, bp2[8], s);  s = fmaf(e2.y, bp2[9], s);
                s = fmaf(e2.z, bp2[10], s); s = fmaf(e2.w, bp2[11], s);
                s = fmaf(e3.x, bp2[12], s); s = fmaf(e3.y, bp2[13], s);
                s = fmaf(e3.z, bp2[14], s); s = fmaf(e3.w, bp2[15], s);
                acc[c] = fmaxf(s, 0.f);
            }
#pragma unroll
            for (int q = 0; q < 4; ++q)
                *(float4*)(zr + cc * 16 + q * 4) =
                    make_float4(acc[q * 4], acc[q * 4 + 1], acc[q * 4 + 2], acc[q * 4 + 3]);
        }
    } else if (bid < 4352) {
        size_t j = ((size_t)(bid - 256) * 256 + tid) * 4;
        float4 v = *(const float4*)(adj + j);
        int n = (int)(j >> 11), c = (int)(j & 2047);
        ushort4 o = make_ushort4(f2bf(v.x), f2bf(v.y), f2bf(v.z), f2bf(v.w));
        *(ushort4*)(Acat + (size_t)n * 4096 + 2048 + c) = o;
    } else if (bid < 12544) {
        size_t j = ((size_t)(bid - 4352) * 256 + tid) * 4;
        float4 v = *(const float4*)(saw + j);
        ushort4 o = make_ushort4(f2bf(v.x), f2bf(v.y), f2bf(v.z), f2bf(v.w));
        *(ushort4*)(sawb + j) = o;
    } else if (bid < 13568) {
        int local = bid - 12544;
        int m0 = (local & 31) * 64, b = local >> 5;
        int c = tid & 63, g = tid >> 6;
#pragma unroll
        for (int r = 0; r < 16; ++r) {
            int mm = g * 16 + r;
            t[mm][c] = f2bf(x[((size_t)b * 2048 + m0 + mm) * 64 + c]);
        }
        __syncthreads();
#pragma unroll
        for (int r = 0; r < 16; ++r) {
            int cc = g * 16 + r;
            xtT[((size_t)b * 64 + cc) * 2048 + m0 + c] = t[c][cc];
        }
        if (mode) {
#pragma unroll
            for (int r = 0; r < 16; ++r) {
                int mm = g * 16 + r;
                xn[((size_t)(m0 + mm)) * 2048 + b * 64 + c] = t[mm][c];
            }
        }
    } else {
        int local = bid - 13568;
        if (local < 16) {
            const int d = local;
            const float* base = Wp + (size_t)d * 12288;    // [k][i][o]
            for (int idx = tid; idx < 12288; idx += 256) {
                int o = idx / 192, ki = idx - o * 192;
                int k = ki >> 6, i = ki & 63;
                float v;
                if (k == 0)      v = base[i * 64 + o] - base[2 * 4096 + i * 64 + o];
                else if (k == 1) v = base[4096 + i * 64 + o];
                else             v = 2.f * base[2 * 4096 + i * 64 + o];
                size_t dst = (size_t)(d * 64 + o) * 192 + ki;
                Wpb[dst] = f2bf(v);
                Wpbf[dst] = v;
            }
        } else {
            const int nb = local - 16;
#pragma unroll
            for (int it = 0; it < 8; ++it) {
                int idx = tid + it * 256;
                int n = nb * 32 + (idx >> 6), o = idx & 63;
                float s = 0.f;
#pragma unroll
                for (int d = 0; d < 16; ++d) s = fmaf(E[n * 16 + d], bp[d * 64 + o], s);
                bias[(size_t)n * 64 + o] = s;
            }
        }
    }
}

// ---------------------------------------------------------------- mid: softmax + wgen
__global__ __launch_bounds__(256)
void mid(const float* __restrict__ zf, u16* __restrict__ Acat,
         const float* __restrict__ E, const float* __restrict__ Wpbf,
         u16* __restrict__ Wnb) {
    __shared__ float red[4];
    __shared__ float Es[32 * 16];
    const int bid = blockIdx.x, tid = threadIdx.x;
    if (bid < 2048) {
        const int n = bid, lane = tid & 63, wave = tid >> 6;
        const float* zr = zf + (size_t)n * 2048;
        float4 a = *(const float4*)(zr + tid * 8);
        float4 b = *(const float4*)(zr + tid * 8 + 4);
        float mx = fmaxf(fmaxf(fmaxf(a.x, a.y), fmaxf(a.z, a.w)),
                         fmaxf(fmaxf(b.x, b.y), fmaxf(b.z, b.w)));
        for (int off = 32; off; off >>= 1) mx = fmaxf(mx, __shfl_down(mx, off, 64));
        if (lane == 0) red[wave] = mx;
        __syncthreads();
        mx = fmaxf(fmaxf(red[0], red[1]), fmaxf(red[2], red[3]));
        __syncthreads();
        float v[8] = {__expf(a.x - mx), __expf(a.y - mx), __expf(a.z - mx), __expf(a.w - mx),
                      __expf(b.x - mx), __expf(b.y - mx), __expf(b.z - mx), __expf(b.w - mx)};
        float sum = v[0] + v[1] + v[2] + v[3] + v[4] + v[5] + v[6] + v[7];
        for (int off = 32; off; off >>= 1) sum += __shfl_down(sum, off, 64);
        if (lane == 0) red[wave] = sum;
        __syncthreads();
        sum = red[0] + red[1] + red[2] + red[3];
        float inv = 1.f / sum;
        u16* orow = Acat + (size_t)n * 4096 + tid * 8;
        *(ushort4*)orow = make_ushort4(f2bf(v[0] * inv), f2bf(v[1] * inv),
                                       f2bf(v[2] * inv), f2bf(v[3] * inv));
        *(ushort4*)(orow + 4) = make_ushort4(f2bf(v[4] * inv), f2bf(v[5] * inv),
                                             f2bf(v[6] * inv), f2bf(v[7] * inv));
    } else {
        const int w = bid - 2048;
        const int c0 = (w % 12) * 1024, n0 = (w / 12) * 32;
        for (int j = tid; j < 512; j += 256) Es[j] = E[(size_t)n0 * 16 + j];
        float4 wf[16];
#pragma unroll
        for (int d = 0; d < 16; ++d)
            wf[d] = *(const float4*)(Wpbf + (size_t)d * 12288 + c0 + tid * 4);
        __syncthreads();
        for (int nl = 0; nl < 32; ++nl) {
            float4 s = make_float4(0.f, 0.f, 0.f, 0.f);
#pragma unroll
            for (int d = 0; d < 16; ++d) {
                float e = Es[nl * 16 + d];
                s.x = fmaf(e, wf[d].x, s.x);
                s.y = fmaf(e, wf[d].y, s.y);
                s.z = fmaf(e, wf[d].z, s.z);
                s.w = fmaf(e, wf[d].w, s.w);
            }
            *(ushort4*)(Wnb + (size_t)(n0 + nl) * 12288 + c0 + tid * 4) =
                make_ushort4(f2bf(s.x), f2bf(s.y), f2bf(s.z), f2bf(s.w));
        }
    }
}

// ---------------------------------------------------------------- GEMM 256x256, BK=64, split-K
// 8 waves (2Mx4N), dbuf LDS (128KB), gl_lds staging, 4 quadrant-phases per K-tile.
// Raw s_barrier (no vmcnt drain) + counted-cover staging: next tile's 8 loads issue at
// phase 0 into the free buffer; vmcnt(0) only at phase 3 (~3 phases of latency cover).
__global__ __launch_bounds__(512, 2)
void gemm_bt256(const u16* __restrict__ A, const u16* __restrict__ Bt,
                u16* __restrict__ Cp, int M, int N, int K, int Kh) {
    __shared__ alignas(16) u16 As[2][256 * 64];
    __shared__ alignas(16) u16 Bs[2][256 * 64];
    const int tid = threadIdx.x, lane = tid & 63, wave = tid >> 6;

    // bijective XCD swizzle of the linearized block id (nwg % 8 == 0 here)
    const int nbx = gridDim.x, nby = gridDim.y, nbz = gridDim.z;
    const int nwg = nbx * nby * nbz;
    int lin = (blockIdx.z * nby + blockIdx.y) * nbx + blockIdx.x;
    if ((nwg & 7) == 0) lin = (lin & 7) * (nwg >> 3) + (lin >> 3);
    const int bz = lin / (nbx * nby);
    const int r2 = lin - bz * nbx * nby;
    const int by = r2 / nbx, bx = r2 - by * nbx;

    const int m0 = by * 256, n0 = bx * 256;
    const int kbeg = bz * Kh;
    const int NT = Kh >> 6;
    const int wm = (wave >> 2) * 128, wn = (wave & 3) * 64;
    const int ml = lane & 15, c0l = lane >> 4;

    // staging geometry: linear LDS dest (slot s -> 16B), pre-swizzled global source
    int sI[4], rowI[4], gcI[4];
#pragma unroll
    for (int r = 0; r < 4; ++r) {
        int s = r * 512 + tid;
        sI[r] = s; rowI[r] = s >> 3; gcI[r] = (s & 7) ^ ((s >> 3) & 7);
    }

    f32x4 acc[8][4] = {};

    // prologue: stage tile 0 into buf 0
#pragma unroll
    for (int r = 0; r < 4; ++r)
        gl_lds16(A + (size_t)(m0 + rowI[r]) * K + kbeg + gcI[r] * 8, &As[0][sI[r] * 8]);
#pragma unroll
    for (int r = 0; r < 4; ++r)
        gl_lds16(Bt + (size_t)(n0 + rowI[r]) * K + kbeg + gcI[r] * 8, &Bs[0][sI[r] * 8]);
    asm volatile("s_waitcnt vmcnt(0)" ::: "memory");
    __builtin_amdgcn_s_barrier();

    for (int t = 0; t < NT; ++t) {
        const int cur = t & 1;
        const u16* Asc = As[cur];
        const u16* Bsc = Bs[cur];

        // phase 0 pre-work: issue next tile's 8 gl_lds into the FREE buffer
        // (its last reads retired before the previous closing barrier)
        if (t + 1 < NT) {
            const int k1 = kbeg + (t + 1) * 64;
            u16* Ad = (u16*)As[cur ^ 1];
            u16* Bd = (u16*)Bs[cur ^ 1];
#pragma unroll
            for (int r = 0; r < 4; ++r)
                gl_lds16(A + (size_t)(m0 + rowI[r]) * K + k1 + gcI[r] * 8, Ad + sI[r] * 8);
#pragma unroll
            for (int r = 0; r < 4; ++r)
                gl_lds16(Bt + (size_t)(n0 + rowI[r]) * K + k1 + gcI[r] * 8, Bd + sI[r] * 8);
        }

        bf16x8 af[4][2], bv[2][2];

        // ---- phase 0: load A(qm=0) + B(qn=0), compute quad (0,0)
#pragma unroll
        for (int i = 0; i < 4; ++i) {
            const int mr = wm + i * 16 + ml;
#pragma unroll
            for (int ks = 0; ks < 2; ++ks)
                af[i][ks] = *(const bf16x8*)(Asc + mr * 64 + (((c0l + ks * 4) ^ (mr & 7)) * 8));
        }
#pragma unroll
        for (int j = 0; j < 2; ++j) {
            const int nr = wn + j * 16 + ml;
#pragma unroll
            for (int ks = 0; ks < 2; ++ks)
                bv[j][ks] = *(const bf16x8*)(Bsc + nr * 64 + (((c0l + ks * 4) ^ (nr & 7)) * 8));
        }
        __builtin_amdgcn_s_barrier();
        asm volatile("s_waitcnt lgkmcnt(0)" ::: "memory");
        __builtin_amdgcn_s_setprio(1);
#pragma unroll
        for (int ks = 0; ks < 2; ++ks)
#pragma unroll
            for (int i = 0; i < 4; ++i)
#pragma unroll
                for (int j = 0; j < 2; ++j)
                    acc[i][j] = __builtin_amdgcn_mfma_f32_16x16x32_bf16(af[i][ks], bv[j][ks], acc[i][j], 0, 0, 0);
        __builtin_amdgcn_s_setprio(0);
        __builtin_amdgcn_s_barrier();

        // ---- phase 1: load B(qn=1), compute quad (0,1) with kept A
#pragma unroll
        for (int j = 0; j < 2; ++j) {
            const int nr = wn + (2 + j) * 16 + ml;
#pragma unroll
            for (int ks = 0; ks < 2; ++ks)
                bv[j][ks] = *(const bf16x8*)(Bsc + nr * 64 + (((c0l + ks * 4) ^ (nr & 7)) * 8));
        }
        __builtin_amdgcn_s_barrier();
        asm volatile("s_waitcnt lgkmcnt(0)" ::: "memory");
        __builtin_amdgcn_s_setprio(1);
#pragma unroll
        for (int ks = 0; ks < 2; ++ks)
#pragma unroll
            for (int i = 0; i < 4; ++i)
#pragma unroll
                for (int j = 0; j < 2; ++j)
                    acc[i][2 + j] = __builtin_amdgcn_mfma_f32_16x16x32_bf16(af[i][ks], bv[j][ks], acc[i][2 + j], 0, 0, 0);
        __builtin_amdgcn_s_setprio(0);
        __builtin_amdgcn_s_barrier();

        // ---- phase 2: load A(qm=1), compute quad (1,1) with kept B
#pragma unroll
        for (int i = 0; i < 4; ++i) {
            const int mr = wm + (4 + i) * 16 + ml;
#pragma unroll
            for (int ks = 0; ks < 2; ++ks)
                af[i][ks] = *(const bf16x8*)(Asc + mr * 64 + (((c0l + ks * 4) ^ (mr & 7)) * 8));
        }
        __builtin_amdgcn_s_barrier();
        asm volatile("s_waitcnt lgkmcnt(0)" ::: "memory");
        __builtin_amdgcn_s_setprio(1);
#pragma unroll
        for (int ks = 0; ks < 2; ++ks)
#pragma unroll
            for (int i = 0; i < 4; ++i)
#pragma unroll
                for (int j = 0; j < 2; ++j)
                    acc[4 + i][2 + j] = __builtin_amdgcn_mfma_f32_16x16x32_bf16(af[i][ks], bv[j][ks], acc[4 + i][2 + j], 0, 0, 0);
        __builtin_amdgcn_s_setprio(0);
        __builtin_amdgcn_s_barrier();

        // ---- phase 3: load B(qn=0), compute quad (1,0) with kept A; then wait staging
#pragma unroll
        for (int j = 0; j < 2; ++j) {
            const int nr = wn + j * 16 + ml;
#pragma unroll
            for (int ks = 0; ks < 2; ++ks)
                bv[j][ks] = *(const bf16x8*)(Bsc + nr * 64 + (((c0l + ks * 4) ^ (nr & 7)) * 8));
        }
        __builtin_amdgcn_s_barrier();
        asm volatile("s_waitcnt lgkmcnt(0)" ::: "memory");
        __builtin_amdgcn_s_setprio(1);
#pragma unroll
        for (int ks = 0; ks < 2; ++ks)
#pragma unroll
            for (int i = 0; i < 4; ++i)
#pragma unroll
                for (int j = 0; j < 2; ++j)
                    acc[4 + i][j] = __builtin_amdgcn_mfma_f32_16x16x32_bf16(af[i][ks], bv[j][ks], acc[4 + i][j], 0, 0, 0);
        __builtin_amdgcn_s_setprio(0);
        asm volatile("s_waitcnt vmcnt(0)" ::: "memory");   // next tile landed
        __builtin_amdgcn_s_barrier();
    }

    const int col_l = lane & 15, rl = (lane >> 4) * 4;
    u16* Cz = Cp + (size_t)bz * M * N;
#pragma unroll
    for (int i = 0; i < 8; ++i)
#pragma unroll
        for (int j = 0; j < 4; ++j)
#pragma unroll
            for (int r = 0; r < 4; ++r) {
                int row = m0 + wm + i * 16 + rl + r;
                int col = n0 + wn + j * 16 + col_l;
                Cz[(size_t)row * N + col] = f2bf(acc[i][j][r]);
            }
}

// ---------------------------------------------------------------- reduce_z
__global__ __launch_bounds__(256)
void reduce_z(const u16* __restrict__ p, const u16* __restrict__ Acat,
              u16* __restrict__ S) {
    size_t j = ((size_t)blockIdx.x * 256 + threadIdx.x) * 4;
    ushort4 p0 = *(const ushort4*)(p + j);
    ushort4 p1 = *(const ushort4*)(p + PSTRIDE + j);
    ushort4 p2 = *(const ushort4*)(p + 2 * PSTRIDE + j);
    ushort4 p3 = *(const ushort4*)(p + 3 * PSTRIDE + j);
    int row = (int)(j >> 11), col = (int)(j & 2047);
    ushort4 sp = *(const ushort4*)(Acat + (size_t)row * 4096 + col);
    ushort4 ad = *(const ushort4*)(Acat + (size_t)row * 4096 + 2048 + col);
    float z0 = bf2f(p0.x) + bf2f(p1.x) + bf2f(p2.x) + bf2f(p3.x);
    float z1 = bf2f(p0.y) + bf2f(p1.y) + bf2f(p2.y) + bf2f(p3.y);
    float z2 = bf2f(p0.z) + bf2f(p1.z) + bf2f(p2.z) + bf2f(p3.z);
    float z3 = bf2f(p0.w) + bf2f(p1.w) + bf2f(p2.w) + bf2f(p3.w);
    float s0 = 1.f / (1.f + __expf(-z0)), s1 = 1.f / (1.f + __expf(-z1));
    float s2 = 1.f / (1.f + __expf(-z2)), s3 = 1.f / (1.f + __expf(-z3));
    ushort4 o = make_ushort4(
        f2bf(s0 * bf2f(ad.x) + (1.f - s0) * bf2f(sp.x)),
        f2bf(s1 * bf2f(ad.y) + (1.f - s1) * bf2f(sp.y)),
        f2bf(s2 * bf2f(ad.z) + (1.f - s2) * bf2f(sp.z)),
        f2bf(s3 * bf2f(ad.w) + (1.f - s3) * bf2f(sp.w)));
    *(ushort4*)(S + j) = o;
}

// ---------------------------------------------------------------- reduceT
__global__ __launch_bounds__(256)
void reduceT(const u16* __restrict__ p, u16* __restrict__ xg1o,
             u16* __restrict__ xg1T, int mode) {
    __shared__ u16 t[64][68];
    int bx = blockIdx.x * 64, by = blockIdx.y * 64;
    int cg = threadIdx.x & 15, rg = threadIdx.x >> 4;
    int b = bx >> 6;
#pragma unroll
    for (int rr = 0; rr < 4; ++rr) {
        int row = rg * 4 + rr;
        size_t idx = (size_t)(by + row) * 2048 + bx + cg * 4;
        ushort4 q0 = *(const ushort4*)(p + idx);
        ushort4 q1 = *(const ushort4*)(p + PSTRIDE + idx);
        ushort4 q2 = *(const ushort4*)(p + 2 * PSTRIDE + idx);
        ushort4 q3 = *(const ushort4*)(p + 3 * PSTRIDE + idx);
        ushort4 v = make_ushort4(
            f2bf(bf2f(q0.x) + bf2f(q1.x) + bf2f(q2.x) + bf2f(q3.x)),
            f2bf(bf2f(q0.y) + bf2f(q1.y) + bf2f(q2.y) + bf2f(q3.y)),
            f2bf(bf2f(q0.z) + bf2f(q1.z) + bf2f(q2.z) + bf2f(q3.z)),
            f2bf(bf2f(q0.w) + bf2f(q1.w) + bf2f(q2.w) + bf2f(q3.w)));
        if (mode) *(ushort4*)(xg1o + idx) = v;
        else      *(ushort4*)(xg1o + ((size_t)b * 2048 + by + row) * 64 + cg * 4) = v;
        *(ushort4*)(&t[row][cg * 4]) = v;
    }
    __syncthreads();
    int c = threadIdx.x & 63, g = threadIdx.x >> 6;
#pragma unroll
    for (int r = 0; r < 16; ++r) {
        int row = g * 16 + r;
        xg1T[(size_t)(bx + row) * 2048 + by + c] = t[c][row];
    }
}

// ---------------------------------------------------------------- gconv_wn (Wn mode)
__global__ __launch_bounds__(256, 4)
void gconv_wn(const u16* __restrict__ xn, const u16* __restrict__ xg1n,
              const u16* __restrict__ p, const u16* __restrict__ Wnb,
              const float* __restrict__ bias, float* __restrict__ out) {
    __shared__ alignas(16) u16 As[32 * 192];
    __shared__ alignas(16) u16 Bs[64 * 192];
    const int n = blockIdx.x, tid = threadIdx.x;
    const int lane = tid & 63, wave = tid >> 6;
    const int wn2 = wave * 16;
    const int ml = lane & 15, c0l = lane >> 4;
    const int col = lane & 15, rl = (lane >> 4) * 4;

#pragma unroll
    for (int it = 0; it < 6; ++it) {
        int s = tid + it * 256;
        int row = s / 24, sc = s - row * 24;
        int gc = (sc & 24) | ((sc ^ row) & 7);
        gl_lds16(Wnb + (size_t)n * 12288 + (size_t)row * 192 + gc * 8, Bs + (size_t)s * 8);
    }
#pragma unroll
    for (int it = 0; it < 3; ++it) {
        int s = tid + it * 256;
        int row = s / 24, sc = s - row * 24;
        int gc = (sc & 24) | ((sc ^ row) & 7);
        u16x8 v;
        if (gc < 8) {
            v = *(const u16x8*)(xn + (size_t)n * 2048 + row * 64 + (gc & 7) * 8);
        } else if (gc < 16) {
            v = *(const u16x8*)(xg1n + (size_t)n * 2048 + row * 64 + (gc & 7) * 8);
        } else {
            const u16* pp = p + (size_t)n * 2048 + row * 64 + (gc & 7) * 8;
            u16x8 q0 = *(const u16x8*)pp;
            u16x8 q1 = *(const u16x8*)(pp + PSTRIDE);
            u16x8 q2 = *(const u16x8*)(pp + 2 * PSTRIDE);
            u16x8 q3 = *(const u16x8*)(pp + 3 * PSTRIDE);
#pragma unroll
            for (int tt = 0; tt < 8; ++tt)
                v[tt] = f2bf(bf2f(q0[tt]) + bf2f(q1[tt]) + bf2f(q2[tt]) + bf2f(q3[tt]));
        }
        *(u16x8*)(As + (size_t)s * 8) = v;
    }
    float bv0 = bias[(size_t)n * 64 + wn2 + col];
    f32x4 acc[2];
#pragma unroll
    for (int mt = 0; mt < 2; ++mt)
#pragma unroll
        for (int r = 0; r < 4; ++r) acc[mt][r] = bv0;
    __syncthreads();

#pragma unroll
    for (int ks = 0; ks < 6; ++ks) {
        int c = c0l + ks * 4;
        int o = wn2 + ml;
        bf16x8 bfrag = *(const bf16x8*)(Bs + (o * 24 + ((c & 24) | ((c ^ (o & 7)) & 7))) * 8);
#pragma unroll
        for (int mt = 0; mt < 2; ++mt) {
            int m = mt * 16 + ml;
            bf16x8 afrag = *(const bf16x8*)(As + (m * 24 + ((c & 24) | ((c ^ (m & 7)) & 7))) * 8);
            acc[mt] = __builtin_amdgcn_mfma_f32_16x16x32_bf16(afrag, bfrag, acc[mt], 0, 0, 0);
        }
    }
#pragma unroll
    for (int mt = 0; mt < 2; ++mt)
#pragma unroll
        for (int r = 0; r < 4; ++r) {
            int b = mt * 16 + rl + r;
            out[((size_t)b * 2048 + n) * 64 + wn2 + col] = acc[mt][r];
        }
}

// ---------------------------------------------------------------- gconv_mfma (legacy fallback)
__global__ __launch_bounds__(256, 2)
void gconv_mfma(const float* __restrict__ x, const u16* __restrict__ xg1,
                const u16* __restrict__ p, const u16* __restrict__ Wpb,
                const float* __restrict__ bias, const float* __restrict__ E,
                float* __restrict__ out) {
    __shared__ alignas(16) float El[16 * 128];
    const int tid = threadIdx.x, lane = tid & 63, wave = tid >> 6;
    const int m0 = blockIdx.x * 128, nb = m0 & 2047, bB = m0 >> 11;
    const int wm = (wave >> 1) * 64, wn = (wave & 1) * 32;
    const int ml = lane & 15, c0l = lane >> 4;
    const int col_l = lane & 15, rl = (lane >> 4) * 4;

#pragma unroll
    for (int it = 0; it < 8; ++it) {
        int idx = tid + it * 256;
        El[idx] = E[(size_t)(nb + (idx & 127)) * 16 + (idx >> 7)];
    }
    __syncthreads();

    bf16x8 af[4][6];
#pragma unroll
    for (int i = 0; i < 4; ++i) {
        const int row = m0 + wm + i * 16 + ml;
        const int n = row & 2047;
#pragma unroll
        for (int ks = 0; ks < 2; ++ks) {
            const float* xp = x + (size_t)row * 64 + (c0l + ks * 4) * 8;
            float4 a = *(const float4*)xp, b4 = *(const float4*)(xp + 4);
            u16x8 v;
            v[0] = f2bf(a.x);  v[1] = f2bf(a.y);  v[2] = f2bf(a.z);  v[3] = f2bf(a.w);
            v[4] = f2bf(b4.x); v[5] = f2bf(b4.y); v[6] = f2bf(b4.z); v[7] = f2bf(b4.w);
            af[i][ks] = __builtin_bit_cast(bf16x8, v);
        }
#pragma unroll
        for (int ks = 2; ks < 4; ++ks)
            af[i][ks] = *(const bf16x8*)(xg1 + (size_t)row * 64 + (c0l + ks * 4 - 8) * 8);
#pragma unroll
        for (int ks = 4; ks < 6; ++ks) {
            const u16* pp = p + (size_t)n * 2048 + bB * 64 + (c0l + ks * 4 - 16) * 8;
            u16x8 q0 = *(const u16x8*)pp;
            u16x8 q1 = *(const u16x8*)(pp + PSTRIDE);
            u16x8 q2 = *(const u16x8*)(pp + 2 * PSTRIDE);
            u16x8 q3 = *(const u16x8*)(pp + 3 * PSTRIDE);
            u16x8 v;
#pragma unroll
            for (int tt = 0; tt < 8; ++tt)
                v[tt] = f2bf(bf2f(q0[tt]) + bf2f(q1[tt]) + bf2f(q2[tt]) + bf2f(q3[tt]));
            af[i][ks] = __builtin_bit_cast(bf16x8, v);
        }
    }

    f32x4 oacc[4][2];
#pragma unroll
    for (int i = 0; i < 4; ++i)
#pragma unroll
        for (int j = 0; j < 2; ++j)
#pragma unroll
            for (int r = 0; r < 4; ++r)
                oacc[i][j][r] = bias[(size_t)(nb + wm + i * 16 + rl + r) * 64 + wn + j * 16 + col_l];

#pragma unroll 2
    for (int d = 0; d < 16; ++d) {
        bf16x8 bv[2][6];
#pragma unroll
        for (int j = 0; j < 2; ++j) {
            const u16* wp = Wpb + (size_t)(d * 64 + wn + j * 16 + ml) * 192 + c0l * 8;
#pragma unroll
            for (int ks = 0; ks < 6; ++ks)
                bv[j][ks] = *(const bf16x8*)(wp + ks * 32);
        }
        f32x4 tmp[4][2] = {};
#pragma unroll
        for (int ks = 0; ks < 6; ++ks)
#pragma unroll
            for (int i = 0; i < 4; ++i)
#pragma unroll
                for (int j = 0; j < 2; ++j)
                    tmp[i][j] = __builtin_amdgcn_mfma_f32_16x16x32_bf16(af[i][ks], bv[j][ks], tmp[i][j], 0, 0, 0);
#pragma unroll
        for (int i = 0; i < 4; ++i) {
            f32x4 ev = *(const f32x4*)(El + d * 128 + wm + i * 16 + rl);
#pragma unroll
            for (int r = 0; r < 4; ++r)
#pragma unroll
                for (int j = 0; j < 2; ++j)
                    oacc[i][j][r] = fmaf(ev[r], tmp[i][j][r], oacc[i][j][r]);
        }
    }
#pragma unroll
    for (int i = 0; i < 4; ++i)
#pragma unroll
        for (int j = 0; j < 2; ++j)
#pragma unroll
            for (int r = 0; r < 4; ++r)
                out[(size_t)(m0 + wm + i * 16 + rl + r) * 64 + wn + j * 16 + col_l] = oacc[i][j][r];
}

// ---------------------------------------------------------------- launch
extern "C" void kernel_launch(void* const* d_in, const int* in_sizes, int n_in,
                              void* d_out, int out_size, void* d_ws, size_t ws_size,
                              hipStream_t stream) {
    const float* x   = (const float*)d_in[0];
    const float* E   = (const float*)d_in[1];
    const float* adj = (const float*)d_in[2];
    const float* Wp  = (const float*)d_in[3];
    const float* bp  = (const float*)d_in[4];
    const float* saw = (const float*)d_in[5];
    float* out = (float*)d_out;

    char* ws = (char*)d_ws;
    const size_t MB = 1u << 20;
    const int wn_mode = (ws_size >= 140 * MB) ? 1 : 0;

    u16*   Acat  = (u16*)(ws);                  // [0,16M)
    u16*   sawb  = (u16*)(ws + 16 * MB);        // [16,32M)
    u16*   XtT   = (u16*)(ws + 32 * MB);        // [32,40M)
    u16*   Wpb   = (u16*)(ws + 40 * MB);        // [40,40.4M) bf16
    float* bias  = (float*)(ws + 41 * MB);      // [41,41.5M)
    float* Wpbf  = (float*)(ws + 42 * MB);      // [42,42.8M) fp32
    float* zf    = (float*)(ws + 48 * MB);      // [48,64M)
    u16*   part  = (u16*)(ws + 48 * MB);        // [48,80M)
    u16*   S_bf  = (u16*)(ws + 16 * MB);        // [16,24M)
    u16*   xg1T  = (u16*)(ws + 24 * MB);        // [24,32M)
    u16*   xg1o  = (u16*)(ws);                  // [0,8M)
    u16*   xn    = (u16*)(ws + 80 * MB);        // [80,88M)   wn only
    u16*   Wnb   = (u16*)(ws + 88 * MB);        // [88,138.4M) wn only

    preamble<<<13648, 256, 0, stream>>>(E, adj, saw, x, Wp, bp, zf, Acat, sawb, XtT,
                                        Wpb, Wpbf, bias, xn, wn_mode);
    mid<<<wn_mode ? 2816 : 2048, 256, 0, stream>>>(zf, Acat, E, Wpbf, Wnb);

    gemm_bt256<<<dim3(8, 8, 4), 512, 0, stream>>>(Acat, sawb, part, 2048, 2048, 4096, 1024);
    reduce_z<<<4096, 256, 0, stream>>>(part, Acat, S_bf);
    gemm_bt256<<<dim3(8, 8, 4), 512, 0, stream>>>(S_bf, XtT, part, 2048, 2048, 2048, 512);
    reduceT<<<dim3(32, 32), 256, 0, stream>>>(part, xg1o, xg1T, wn_mode);
    gemm_bt256<<<dim3(8, 8, 4), 512, 0, stream>>>(S_bf, xg1T, part, 2048, 2048, 2048, 512);

    if (wn_mode)
        gconv_wn<<<2048, 256, 0, stream>>>(xn, xg1o, part, Wnb, bias, out);
    else
        gconv_mfma<<<512, 256, 0, stream>>>(x, xg1o, part, Wpb, bias, E, out);
}

// Round 2
// 276.326 us; speedup vs baseline: 1.0580x; 1.0580x over previous
//
#include <hip/hip_runtime.h>

// AVWGCN: B=32, N=2048, C=64, O=64, K=3, D=16
// R15 changes vs R14 (gemm_bt256 61us, MfmaUtil 21%: per-tile vmcnt(0) drain + burst
// staging = the m218 "drain0" anti-pattern, ~5Kcyc/tile stall):
//  - gemm_bt256: counted-vmcnt pipeline (T4). Staging spread 2 chunks/phase:
//    ph0: B0,B1(t+1); ph1: B2,B3(t+1); ph2: A0,A2(t+1); ph3: A1,A3(t+1).
//    Waits: end-ph1 vmcnt(4) (A1,A3(t) landed; 4 B-chunks stay in flight),
//    end-ph3 vmcnt(2) (B+A0,A2(t+1) landed; A1,A3(t+1) stay in flight).
//    Queue never drains to 0 in the main loop; last tile peeled with vmcnt(0).
//    Both waits precede a closing s_barrier -> cross-wave LDS visibility ordered.
// Rest identical to R14 (256^2 tile, 4 quadrant-phases, XCD swizzle, fused pre/mid).

typedef unsigned short u16;
typedef float f32x4 __attribute__((ext_vector_type(4)));
typedef __bf16 bf16x8 __attribute__((ext_vector_type(8)));
typedef unsigned short u16x8 __attribute__((ext_vector_type(8)));

#define PSTRIDE ((size_t)2048 * 2048)

__device__ __forceinline__ u16 f2bf(float f) {
    unsigned u = __float_as_uint(f);
    u += 0x7FFFu + ((u >> 16) & 1u);   // RNE
    return (u16)(u >> 16);
}
__device__ __forceinline__ float bf2f(u16 h) {
    return __uint_as_float((unsigned)h << 16);
}
__device__ __forceinline__ void gl_lds16(const void* g, void* l) {
    __builtin_amdgcn_global_load_lds(
        (const __attribute__((address_space(1))) unsigned*)g,
        (__attribute__((address_space(3))) unsigned*)l, 16, 0, 0);
}

// ---------------------------------------------------------------- preamble (fused)
__global__ __launch_bounds__(256)
void preamble(const float* __restrict__ E, const float* __restrict__ adj,
              const float* __restrict__ saw, const float* __restrict__ x,
              const float* __restrict__ Wp, const float* __restrict__ bp,
              float* __restrict__ zf, u16* __restrict__ Acat,
              u16* __restrict__ sawb, u16* __restrict__ xtT,
              u16* __restrict__ Wpb, float* __restrict__ Wpbf,
              float* __restrict__ bias, u16* __restrict__ xn, int mode) {
    __shared__ u16 t[64][65];
    __shared__ float Bp[1024];
    const int bid = blockIdx.x, tid = threadIdx.x;

    if (bid < 256) {
        const int c0 = (bid & 31) * 64, r0 = (bid >> 5) * 256;
        const int r = r0 + tid;
        const float4* Er = (const float4*)(E + (size_t)r * 16);
        float4 e0 = Er[0], e1 = Er[1], e2 = Er[2], e3 = Er[3];
        *(float4*)(Bp + tid * 4) = *(const float4*)(E + (size_t)c0 * 16 + tid * 4);
        __syncthreads();
        float* zr = zf + (size_t)r * 2048 + c0;
#pragma unroll
        for (int cc = 0; cc < 4; ++cc) {
            float acc[16];
#pragma unroll
            for (int c = 0; c < 16; ++c) {
                const float* bp2 = Bp + (cc * 16 + c) * 16;
                float s = 0.f;
                s = fmaf(e0.x, bp2[0], s);  s = fmaf(e0.y, bp2[1], s);
                s = fmaf(e0.z, bp2[2], s);  s = fmaf(e0.w, bp2[3], s);
                s = fmaf(e1.x, bp2[4], s);  s = fmaf(e1.y, bp2[5], s);
                s = fmaf(e1.z, bp2[6], s);  s = fmaf(e1.w, bp2[7], s);
                s = fmaf(e2.x, bp2[8], s);  s = fmaf(e2.y, bp2[9], s);
                s = fmaf(e2.z, bp2[10], s); s = fmaf(e2.w, bp2[11], s);
                s = fmaf(e3.x, bp2[12], s); s = fmaf(e3.y, bp2[13], s);
                s = fmaf(e3.z, bp2[14], s); s = fmaf(e3.w, bp2[15], s);
                acc[c] = fmaxf(s, 0.f);
            }
#pragma unroll
            for (int q = 0; q < 4; ++q)
                *(float4*)(zr + cc * 16 + q * 4) =
                    make_float4(acc[q * 4], acc[q * 4 + 1], acc[q * 4 + 2], acc[q * 4 + 3]);
        }
    } else if (bid < 4352) {
        size_t j = ((size_t)(bid - 256) * 256 + tid) * 4;
        float4 v = *(const float4*)(adj + j);
        int n = (int)(j >> 11), c = (int)(j & 2047);
        ushort4 o = make_ushort4(f2bf(v.x), f2bf(v.y), f2bf(v.z), f2bf(v.w));
        *(ushort4*)(Acat + (size_t)n * 4096 + 2048 + c) = o;
    } else if (bid < 12544) {
        size_t j = ((size_t)(bid - 4352) * 256 + tid) * 4;
        float4 v = *(const float4*)(saw + j);
        ushort4 o = make_ushort4(f2bf(v.x), f2bf(v.y), f2bf(v.z), f2bf(v.w));
        *(ushort4*)(sawb + j) = o;
    } else if (bid < 13568) {
        int local = bid - 12544;
        int m0 = (local & 31) * 64, b = local >> 5;
        int c = tid & 63, g = tid >> 6;
#pragma unroll
        for (int r = 0; r < 16; ++r) {
            int mm = g * 16 + r;
            t[mm][c] = f2bf(x[((size_t)b * 2048 + m0 + mm) * 64 + c]);
        }
        __syncthreads();
#pragma unroll
        for (int r = 0; r < 16; ++r) {
            int cc = g * 16 + r;
            xtT[((size_t)b * 64 + cc) * 2048 + m0 + c] = t[c][cc];
        }
        if (mode) {
#pragma unroll
            for (int r = 0; r < 16; ++r) {
                int mm = g * 16 + r;
                xn[((size_t)(m0 + mm)) * 2048 + b * 64 + c] = t[mm][c];
            }
        }
    } else {
        int local = bid - 13568;
        if (local < 16) {
            const int d = local;
            const float* base = Wp + (size_t)d * 12288;    // [k][i][o]
            for (int idx = tid; idx < 12288; idx += 256) {
                int o = idx / 192, ki = idx - o * 192;
                int k = ki >> 6, i = ki & 63;
                float v;
                if (k == 0)      v = base[i * 64 + o] - base[2 * 4096 + i * 64 + o];
                else if (k == 1) v = base[4096 + i * 64 + o];
                else             v = 2.f * base[2 * 4096 + i * 64 + o];
                size_t dst = (size_t)(d * 64 + o) * 192 + ki;
                Wpb[dst] = f2bf(v);
                Wpbf[dst] = v;
            }
        } else {
            const int nb = local - 16;
#pragma unroll
            for (int it = 0; it < 8; ++it) {
                int idx = tid + it * 256;
                int n = nb * 32 + (idx >> 6), o = idx & 63;
                float s = 0.f;
#pragma unroll
                for (int d = 0; d < 16; ++d) s = fmaf(E[n * 16 + d], bp[d * 64 + o], s);
                bias[(size_t)n * 64 + o] = s;
            }
        }
    }
}

// ---------------------------------------------------------------- mid: softmax + wgen
__global__ __launch_bounds__(256)
void mid(const float* __restrict__ zf, u16* __restrict__ Acat,
         const float* __restrict__ E, const float* __restrict__ Wpbf,
         u16* __restrict__ Wnb) {
    __shared__ float red[4];
    __shared__ float Es[32 * 16];
    const int bid = blockIdx.x, tid = threadIdx.x;
    if (bid < 2048) {
        const int n = bid, lane = tid & 63, wave = tid >> 6;
        const float* zr = zf + (size_t)n * 2048;
        float4 a = *(const float4*)(zr + tid * 8);
        float4 b = *(const float4*)(zr + tid * 8 + 4);
        float mx = fmaxf(fmaxf(fmaxf(a.x, a.y), fmaxf(a.z, a.w)),
                         fmaxf(fmaxf(b.x, b.y), fmaxf(b.z, b.w)));
        for (int off = 32; off; off >>= 1) mx = fmaxf(mx, __shfl_down(mx, off, 64));
        if (lane == 0) red[wave] = mx;
        __syncthreads();
        mx = fmaxf(fmaxf(red[0], red[1]), fmaxf(red[2], red[3]));
        __syncthreads();
        float v[8] = {__expf(a.x - mx), __expf(a.y - mx), __expf(a.z - mx), __expf(a.w - mx),
                      __expf(b.x - mx), __expf(b.y - mx), __expf(b.z - mx), __expf(b.w - mx)};
        float sum = v[0] + v[1] + v[2] + v[3] + v[4] + v[5] + v[6] + v[7];
        for (int off = 32; off; off >>= 1) sum += __shfl_down(sum, off, 64);
        if (lane == 0) red[wave] = sum;
        __syncthreads();
        sum = red[0] + red[1] + red[2] + red[3];
        float inv = 1.f / sum;
        u16* orow = Acat + (size_t)n * 4096 + tid * 8;
        *(ushort4*)orow = make_ushort4(f2bf(v[0] * inv), f2bf(v[1] * inv),
                                       f2bf(v[2] * inv), f2bf(v[3] * inv));
        *(ushort4*)(orow + 4) = make_ushort4(f2bf(v[4] * inv), f2bf(v[5] * inv),
                                             f2bf(v[6] * inv), f2bf(v[7] * inv));
    } else {
        const int w = bid - 2048;
        const int c0 = (w % 12) * 1024, n0 = (w / 12) * 32;
        for (int j = tid; j < 512; j += 256) Es[j] = E[(size_t)n0 * 16 + j];
        float4 wf[16];
#pragma unroll
        for (int d = 0; d < 16; ++d)
            wf[d] = *(const float4*)(Wpbf + (size_t)d * 12288 + c0 + tid * 4);
        __syncthreads();
        for (int nl = 0; nl < 32; ++nl) {
            float4 s = make_float4(0.f, 0.f, 0.f, 0.f);
#pragma unroll
            for (int d = 0; d < 16; ++d) {
                float e = Es[nl * 16 + d];
                s.x = fmaf(e, wf[d].x, s.x);
                s.y = fmaf(e, wf[d].y, s.y);
                s.z = fmaf(e, wf[d].z, s.z);
                s.w = fmaf(e, wf[d].w, s.w);
            }
            *(ushort4*)(Wnb + (size_t)(n0 + nl) * 12288 + c0 + tid * 4) =
                make_ushort4(f2bf(s.x), f2bf(s.y), f2bf(s.z), f2bf(s.w));
        }
    }
}

// ---------------------------------------------------------------- GEMM 256x256, BK=64, split-K
// 8 waves (2Mx4N), dbuf LDS (128KB), gl_lds staging spread 2 chunks/phase, counted vmcnt
// (never 0 in main loop), 4 quadrant-phases per K-tile, raw s_barrier + setprio.
__global__ __launch_bounds__(512, 2)
void gemm_bt256(const u16* __restrict__ A, const u16* __restrict__ Bt,
                u16* __restrict__ Cp, int M, int N, int K, int Kh) {
    __shared__ alignas(16) u16 As[2][256 * 64];
    __shared__ alignas(16) u16 Bs[2][256 * 64];
    const int tid = threadIdx.x, lane = tid & 63, wave = tid >> 6;

    // bijective XCD swizzle of the linearized block id (nwg % 8 == 0 here)
    const int nbx = gridDim.x, nby = gridDim.y, nbz = gridDim.z;
    const int nwg = nbx * nby * nbz;
    int lin = (blockIdx.z * nby + blockIdx.y) * nbx + blockIdx.x;
    if ((nwg & 7) == 0) lin = (lin & 7) * (nwg >> 3) + (lin >> 3);
    const int bz = lin / (nbx * nby);
    const int r2 = lin - bz * nbx * nby;
    const int by = r2 / nbx, bx = r2 - by * nbx;

    const int m0 = by * 256, n0 = bx * 256;
    const int kbeg = bz * Kh;
    const int NT = Kh >> 6;
    const int wm = (wave >> 2) * 128, wn = (wave & 3) * 64;
    const int ml = lane & 15, c0l = lane >> 4;

    // staging geometry: chunk r covers rows [64r, 64r+64) of the 256-row tile;
    // linear LDS dest (slot s -> 16B), pre-swizzled global source column.
    int sI[4], rowI[4], gcI[4];
#pragma unroll
    for (int r = 0; r < 4; ++r) {
        int s = r * 512 + tid;
        sI[r] = s; rowI[r] = s >> 3; gcI[r] = (s & 7) ^ ((s >> 3) & 7);
    }

    f32x4 acc[8][4] = {};
    bf16x8 af[4][2], bv[2][2];

// staging macros: chunk r of tile with K-offset kt into buffer buf
#define LOADA(r_, kt_, buf_) \
    gl_lds16(A + (size_t)(m0 + rowI[r_]) * K + (kt_) + gcI[r_] * 8, \
             &As[buf_][sI[r_] * 8])
#define LOADB(r_, kt_, buf_) \
    gl_lds16(Bt + (size_t)(n0 + rowI[r_]) * K + (kt_) + gcI[r_] * 8, \
             &Bs[buf_][sI[r_] * 8])

// ds-read macros: A-quarter qa (64 rows of the wave's 128-row strip),
// B-eighth qb (32 cols of the wave's 64-col strip)
#define DSRA(qa_) \
    _Pragma("unroll") \
    for (int i = 0; i < 4; ++i) { \
        const int mr = wm + (qa_) * 64 + i * 16 + ml; \
        _Pragma("unroll") \
        for (int ks = 0; ks < 2; ++ks) \
            af[i][ks] = *(const bf16x8*)(Asc + mr * 64 + (((c0l + ks * 4) ^ (mr & 7)) * 8)); \
    }
#define DSRB(qb_) \
    _Pragma("unroll") \
    for (int j = 0; j < 2; ++j) { \
        const int nr = wn + (qb_) * 32 + j * 16 + ml; \
        _Pragma("unroll") \
        for (int ks = 0; ks < 2; ++ks) \
            bv[j][ks] = *(const bf16x8*)(Bsc + nr * 64 + (((c0l + ks * 4) ^ (nr & 7)) * 8)); \
    }
// MFMA cluster for C-quadrant (io, jo)
#define MMQ(io_, jo_) \
    __builtin_amdgcn_s_barrier(); \
    asm volatile("s_waitcnt lgkmcnt(0)" ::: "memory"); \
    __builtin_amdgcn_s_setprio(1); \
    _Pragma("unroll") \
    for (int ks = 0; ks < 2; ++ks) \
        _Pragma("unroll") \
        for (int i = 0; i < 4; ++i) \
            _Pragma("unroll") \
            for (int j = 0; j < 2; ++j) \
                acc[(io_) + i][(jo_) + j] = __builtin_amdgcn_mfma_f32_16x16x32_bf16( \
                    af[i][ks], bv[j][ks], acc[(io_) + i][(jo_) + j], 0, 0, 0); \
    __builtin_amdgcn_s_setprio(0);

    // prologue: stage tile 0 into buf 0, drain once
#pragma unroll
    for (int r = 0; r < 4; ++r) LOADA(r, kbeg, 0);
#pragma unroll
    for (int r = 0; r < 4; ++r) LOADB(r, kbeg, 0);
    asm volatile("s_waitcnt vmcnt(0)" ::: "memory");
    __builtin_amdgcn_s_barrier();

    // main loop: tiles 0..NT-2, each issues tile t+1 spread across its 4 phases
    for (int t = 0; t < NT - 1; ++t) {
        const int cur = t & 1, nxt = cur ^ 1;
        const u16* Asc = As[cur];
        const u16* Bsc = Bs[cur];
        const int k1 = kbeg + (t + 1) * 64;

        // ph0: quad (0,0)
        DSRA(0); DSRB(0);
        LOADB(0, k1, nxt); LOADB(1, k1, nxt);
        MMQ(0, 0);
        __builtin_amdgcn_s_barrier();

        // ph1: quad (0,1); end-wait: A1,A3(t) landed (4 B-chunks stay in flight)
        DSRB(1);
        LOADB(2, k1, nxt); LOADB(3, k1, nxt);
        MMQ(0, 2);
        asm volatile("s_waitcnt vmcnt(4)" ::: "memory");
        __builtin_amdgcn_s_barrier();

        // ph2: quad (1,1)
        DSRA(1);
        LOADA(0, k1, nxt); LOADA(2, k1, nxt);
        MMQ(4, 2);
        __builtin_amdgcn_s_barrier();

        // ph3: quad (1,0); end-wait: B(t+1)+A0,A2(t+1) landed (A1,A3(t+1) in flight)
        DSRB(0);
        LOADA(1, k1, nxt); LOADA(3, k1, nxt);
        MMQ(4, 0);
        asm volatile("s_waitcnt vmcnt(2)" ::: "memory");
        __builtin_amdgcn_s_barrier();
    }

    // peeled last tile: no staging; vmcnt(0) before ph2's consumers (A1,A3 of this tile)
    {
        const int cur = (NT - 1) & 1;
        const u16* Asc = As[cur];
        const u16* Bsc = Bs[cur];

        DSRA(0); DSRB(0);
        MMQ(0, 0);
        __builtin_amdgcn_s_barrier();

        DSRB(1);
        MMQ(0, 2);
        asm volatile("s_waitcnt vmcnt(0)" ::: "memory");
        __builtin_amdgcn_s_barrier();

        DSRA(1);
        MMQ(4, 2);
        __builtin_amdgcn_s_barrier();

        DSRB(0);
        MMQ(4, 0);
    }

#undef LOADA
#undef LOADB
#undef DSRA
#undef DSRB
#undef MMQ

    const int col_l = lane & 15, rl = (lane >> 4) * 4;
    u16* Cz = Cp + (size_t)bz * M * N;
#pragma unroll
    for (int i = 0; i < 8; ++i)
#pragma unroll
        for (int j = 0; j < 4; ++j)
#pragma unroll
            for (int r = 0; r < 4; ++r) {
                int row = m0 + wm + i * 16 + rl + r;
                int col = n0 + wn + j * 16 + col_l;
                Cz[(size_t)row * N + col] = f2bf(acc[i][j][r]);
            }
}

// ---------------------------------------------------------------- reduce_z
__global__ __launch_bounds__(256)
void reduce_z(const u16* __restrict__ p, const u16* __restrict__ Acat,
              u16* __restrict__ S) {
    size_t j = ((size_t)blockIdx.x * 256 + threadIdx.x) * 4;
    ushort4 p0 = *(const ushort4*)(p + j);
    ushort4 p1 = *(const ushort4*)(p + PSTRIDE + j);
    ushort4 p2 = *(const ushort4*)(p + 2 * PSTRIDE + j);
    ushort4 p3 = *(const ushort4*)(p + 3 * PSTRIDE + j);
    int row = (int)(j >> 11), col = (int)(j & 2047);
    ushort4 sp = *(const ushort4*)(Acat + (size_t)row * 4096 + col);
    ushort4 ad = *(const ushort4*)(Acat + (size_t)row * 4096 + 2048 + col);
    float z0 = bf2f(p0.x) + bf2f(p1.x) + bf2f(p2.x) + bf2f(p3.x);
    float z1 = bf2f(p0.y) + bf2f(p1.y) + bf2f(p2.y) + bf2f(p3.y);
    float z2 = bf2f(p0.z) + bf2f(p1.z) + bf2f(p2.z) + bf2f(p3.z);
    float z3 = bf2f(p0.w) + bf2f(p1.w) + bf2f(p2.w) + bf2f(p3.w);
    float s0 = 1.f / (1.f + __expf(-z0)), s1 = 1.f / (1.f + __expf(-z1));
    float s2 = 1.f / (1.f + __expf(-z2)), s3 = 1.f / (1.f + __expf(-z3));
    ushort4 o = make_ushort4(
        f2bf(s0 * bf2f(ad.x) + (1.f - s0) * bf2f(sp.x)),
        f2bf(s1 * bf2f(ad.y) + (1.f - s1) * bf2f(sp.y)),
        f2bf(s2 * bf2f(ad.z) + (1.f - s2) * bf2f(sp.z)),
        f2bf(s3 * bf2f(ad.w) + (1.f - s3) * bf2f(sp.w)));
    *(ushort4*)(S + j) = o;
}

// ---------------------------------------------------------------- reduceT
__global__ __launch_bounds__(256)
void reduceT(const u16* __restrict__ p, u16* __restrict__ xg1o,
             u16* __restrict__ xg1T, int mode) {
    __shared__ u16 t[64][68];
    int bx = blockIdx.x * 64, by = blockIdx.y * 64;
    int cg = threadIdx.x & 15, rg = threadIdx.x >> 4;
    int b = bx >> 6;
#pragma unroll
    for (int rr = 0; rr < 4; ++rr) {
        int row = rg * 4 + rr;
        size_t idx = (size_t)(by + row) * 2048 + bx + cg * 4;
        ushort4 q0 = *(const ushort4*)(p + idx);
        ushort4 q1 = *(const ushort4*)(p + PSTRIDE + idx);
        ushort4 q2 = *(const ushort4*)(p + 2 * PSTRIDE + idx);
        ushort4 q3 = *(const ushort4*)(p + 3 * PSTRIDE + idx);
        ushort4 v = make_ushort4(
            f2bf(bf2f(q0.x) + bf2f(q1.x) + bf2f(q2.x) + bf2f(q3.x)),
            f2bf(bf2f(q0.y) + bf2f(q1.y) + bf2f(q2.y) + bf2f(q3.y)),
            f2bf(bf2f(q0.z) + bf2f(q1.z) + bf2f(q2.z) + bf2f(q3.z)),
            f2bf(bf2f(q0.w) + bf2f(q1.w) + bf2f(q2.w) + bf2f(q3.w)));
        if (mode) *(ushort4*)(xg1o + idx) = v;
        else      *(ushort4*)(xg1o + ((size_t)b * 2048 + by + row) * 64 + cg * 4) = v;
        *(ushort4*)(&t[row][cg * 4]) = v;
    }
    __syncthreads();
    int c = threadIdx.x & 63, g = threadIdx.x >> 6;
#pragma unroll
    for (int r = 0; r < 16; ++r) {
        int row = g * 16 + r;
        xg1T[(size_t)(bx + row) * 2048 + by + c] = t[c][row];
    }
}

// ---------------------------------------------------------------- gconv_wn (Wn mode)
__global__ __launch_bounds__(256, 4)
void gconv_wn(const u16* __restrict__ xn, const u16* __restrict__ xg1n,
              const u16* __restrict__ p, const u16* __restrict__ Wnb,
              const float* __restrict__ bias, float* __restrict__ out) {
    __shared__ alignas(16) u16 As[32 * 192];
    __shared__ alignas(16) u16 Bs[64 * 192];
    const int n = blockIdx.x, tid = threadIdx.x;
    const int lane = tid & 63, wave = tid >> 6;
    const int wn2 = wave * 16;
    const int ml = lane & 15, c0l = lane >> 4;
    const int col = lane & 15, rl = (lane >> 4) * 4;

#pragma unroll
    for (int it = 0; it < 6; ++it) {
        int s = tid + it * 256;
        int row = s / 24, sc = s - row * 24;
        int gc = (sc & 24) | ((sc ^ row) & 7);
        gl_lds16(Wnb + (size_t)n * 12288 + (size_t)row * 192 + gc * 8, Bs + (size_t)s * 8);
    }
#pragma unroll
    for (int it = 0; it < 3; ++it) {
        int s = tid + it * 256;
        int row = s / 24, sc = s - row * 24;
        int gc = (sc & 24) | ((sc ^ row) & 7);
        u16x8 v;
        if (gc < 8) {
            v = *(const u16x8*)(xn + (size_t)n * 2048 + row * 64 + (gc & 7) * 8);
        } else if (gc < 16) {
            v = *(const u16x8*)(xg1n + (size_t)n * 2048 + row * 64 + (gc & 7) * 8);
        } else {
            const u16* pp = p + (size_t)n * 2048 + row * 64 + (gc & 7) * 8;
            u16x8 q0 = *(const u16x8*)pp;
            u16x8 q1 = *(const u16x8*)(pp + PSTRIDE);
            u16x8 q2 = *(const u16x8*)(pp + 2 * PSTRIDE);
            u16x8 q3 = *(const u16x8*)(pp + 3 * PSTRIDE);
#pragma unroll
            for (int tt = 0; tt < 8; ++tt)
                v[tt] = f2bf(bf2f(q0[tt]) + bf2f(q1[tt]) + bf2f(q2[tt]) + bf2f(q3[tt]));
        }
        *(u16x8*)(As + (size_t)s * 8) = v;
    }
    float bv0 = bias[(size_t)n * 64 + wn2 + col];
    f32x4 acc[2];
#pragma unroll
    for (int mt = 0; mt < 2; ++mt)
#pragma unroll
        for (int r = 0; r < 4; ++r) acc[mt][r] = bv0;
    __syncthreads();

#pragma unroll
    for (int ks = 0; ks < 6; ++ks) {
        int c = c0l + ks * 4;
        int o = wn2 + ml;
        bf16x8 bfrag = *(const bf16x8*)(Bs + (o * 24 + ((c & 24) | ((c ^ (o & 7)) & 7))) * 8);
#pragma unroll
        for (int mt = 0; mt < 2; ++mt) {
            int m = mt * 16 + ml;
            bf16x8 afrag = *(const bf16x8*)(As + (m * 24 + ((c & 24) | ((c ^ (m & 7)) & 7))) * 8);
            acc[mt] = __builtin_amdgcn_mfma_f32_16x16x32_bf16(afrag, bfrag, acc[mt], 0, 0, 0);
        }
    }
#pragma unroll
    for (int mt = 0; mt < 2; ++mt)
#pragma unroll
        for (int r = 0; r < 4; ++r) {
            int b = mt * 16 + rl + r;
            out[((size_t)b * 2048 + n) * 64 + wn2 + col] = acc[mt][r];
        }
}

// ---------------------------------------------------------------- gconv_mfma (legacy fallback)
__global__ __launch_bounds__(256, 2)
void gconv_mfma(const float* __restrict__ x, const u16* __restrict__ xg1,
                const u16* __restrict__ p, const u16* __restrict__ Wpb,
                const float* __restrict__ bias, const float* __restrict__ E,
                float* __restrict__ out) {
    __shared__ alignas(16) float El[16 * 128];
    const int tid = threadIdx.x, lane = tid & 63, wave = tid >> 6;
    const int m0 = blockIdx.x * 128, nb = m0 & 2047, bB = m0 >> 11;
    const int wm = (wave >> 1) * 64, wn = (wave & 1) * 32;
    const int ml = lane & 15, c0l = lane >> 4;
    const int col_l = lane & 15, rl = (lane >> 4) * 4;

#pragma unroll
    for (int it = 0; it < 8; ++it) {
        int idx = tid + it * 256;
        El[idx] = E[(size_t)(nb + (idx & 127)) * 16 + (idx >> 7)];
    }
    __syncthreads();

    bf16x8 af[4][6];
#pragma unroll
    for (int i = 0; i < 4; ++i) {
        const int row = m0 + wm + i * 16 + ml;
        const int n = row & 2047;
#pragma unroll
        for (int ks = 0; ks < 2; ++ks) {
            const float* xp = x + (size_t)row * 64 + (c0l + ks * 4) * 8;
            float4 a = *(const float4*)xp, b4 = *(const float4*)(xp + 4);
            u16x8 v;
            v[0] = f2bf(a.x);  v[1] = f2bf(a.y);  v[2] = f2bf(a.z);  v[3] = f2bf(a.w);
            v[4] = f2bf(b4.x); v[5] = f2bf(b4.y); v[6] = f2bf(b4.z); v[7] = f2bf(b4.w);
            af[i][ks] = __builtin_bit_cast(bf16x8, v);
        }
#pragma unroll
        for (int ks = 2; ks < 4; ++ks)
            af[i][ks] = *(const bf16x8*)(xg1 + (size_t)row * 64 + (c0l + ks * 4 - 8) * 8);
#pragma unroll
        for (int ks = 4; ks < 6; ++ks) {
            const u16* pp = p + (size_t)n * 2048 + bB * 64 + (c0l + ks * 4 - 16) * 8;
            u16x8 q0 = *(const u16x8*)pp;
            u16x8 q1 = *(const u16x8*)(pp + PSTRIDE);
            u16x8 q2 = *(const u16x8*)(pp + 2 * PSTRIDE);
            u16x8 q3 = *(const u16x8*)(pp + 3 * PSTRIDE);
            u16x8 v;
#pragma unroll
            for (int tt = 0; tt < 8; ++tt)
                v[tt] = f2bf(bf2f(q0[tt]) + bf2f(q1[tt]) + bf2f(q2[tt]) + bf2f(q3[tt]));
            af[i][ks] = __builtin_bit_cast(bf16x8, v);
        }
    }

    f32x4 oacc[4][2];
#pragma unroll
    for (int i = 0; i < 4; ++i)
#pragma unroll
        for (int j = 0; j < 2; ++j)
#pragma unroll
            for (int r = 0; r < 4; ++r)
                oacc[i][j][r] = bias[(size_t)(nb + wm + i * 16 + rl + r) * 64 + wn + j * 16 + col_l];

#pragma unroll 2
    for (int d = 0; d < 16; ++d) {
        bf16x8 bv[2][6];
#pragma unroll
        for (int j = 0; j < 2; ++j) {
            const u16* wp = Wpb + (size_t)(d * 64 + wn + j * 16 + ml) * 192 + c0l * 8;
#pragma unroll
            for (int ks = 0; ks < 6; ++ks)
                bv[j][ks] = *(const bf16x8*)(wp + ks * 32);
        }
        f32x4 tmp[4][2] = {};
#pragma unroll
        for (int ks = 0; ks < 6; ++ks)
#pragma unroll
            for (int i = 0; i < 4; ++i)
#pragma unroll
                for (int j = 0; j < 2; ++j)
                    tmp[i][j] = __builtin_amdgcn_mfma_f32_16x16x32_bf16(af[i][ks], bv[j][ks], tmp[i][j], 0, 0, 0);
#pragma unroll
        for (int i = 0; i < 4; ++i) {
            f32x4 ev = *(const f32x4*)(El + d * 128 + wm + i * 16 + rl);
#pragma unroll
            for (int r = 0; r < 4; ++r)
#pragma unroll
                for (int j = 0; j < 2; ++j)
                    oacc[i][j][r] = fmaf(ev[r], tmp[i][j][r], oacc[i][j][r]);
        }
    }
#pragma unroll
    for (int i = 0; i < 4; ++i)
#pragma unroll
        for (int j = 0; j < 2; ++j)
#pragma unroll
            for (int r = 0; r < 4; ++r)
                out[(size_t)(m0 + wm + i * 16 + rl + r) * 64 + wn + j * 16 + col_l] = oacc[i][j][r];
}

// ---------------------------------------------------------------- launch
extern "C" void kernel_launch(void* const* d_in, const int* in_sizes, int n_in,
                              void* d_out, int out_size, void* d_ws, size_t ws_size,
                              hipStream_t stream) {
    const float* x   = (const float*)d_in[0];
    const float* E   = (const float*)d_in[1];
    const float* adj = (const float*)d_in[2];
    const float* Wp  = (const float*)d_in[3];
    const float* bp  = (const float*)d_in[4];
    const float* saw = (const float*)d_in[5];
    float* out = (float*)d_out;

    char* ws = (char*)d_ws;
    const size_t MB = 1u << 20;
    const int wn_mode = (ws_size >= 140 * MB) ? 1 : 0;

    u16*   Acat  = (u16*)(ws);                  // [0,16M)
    u16*   sawb  = (u16*)(ws + 16 * MB);        // [16,32M)
    u16*   XtT   = (u16*)(ws + 32 * MB);        // [32,40M)
    u16*   Wpb   = (u16*)(ws + 40 * MB);        // [40,40.4M) bf16
    float* bias  = (float*)(ws + 41 * MB);      // [41,41.5M)
    float* Wpbf  = (float*)(ws + 42 * MB);      // [42,42.8M) fp32
    float* zf    = (float*)(ws + 48 * MB);      // [48,64M)
    u16*   part  = (u16*)(ws + 48 * MB);        // [48,80M)
    u16*   S_bf  = (u16*)(ws + 16 * MB);        // [16,24M)
    u16*   xg1T  = (u16*)(ws + 24 * MB);        // [24,32M)
    u16*   xg1o  = (u16*)(ws);                  // [0,8M)
    u16*   xn    = (u16*)(ws + 80 * MB);        // [80,88M)   wn only
    u16*   Wnb   = (u16*)(ws + 88 * MB);        // [88,138.4M) wn only

    preamble<<<13648, 256, 0, stream>>>(E, adj, saw, x, Wp, bp, zf, Acat, sawb, XtT,
                                        Wpb, Wpbf, bias, xn, wn_mode);
    mid<<<wn_mode ? 2816 : 2048, 256, 0, stream>>>(zf, Acat, E, Wpbf, Wnb);

    gemm_bt256<<<dim3(8, 8, 4), 512, 0, stream>>>(Acat, sawb, part, 2048, 2048, 4096, 1024);
    reduce_z<<<4096, 256, 0, stream>>>(part, Acat, S_bf);
    gemm_bt256<<<dim3(8, 8, 4), 512, 0, stream>>>(S_bf, XtT, part, 2048, 2048, 2048, 512);
    reduceT<<<dim3(32, 32), 256, 0, stream>>>(part, xg1o, xg1T, wn_mode);
    gemm_bt256<<<dim3(8, 8, 4), 512, 0, stream>>>(S_bf, xg1T, part, 2048, 2048, 2048, 512);

    if (wn_mode)
        gconv_wn<<<2048, 256, 0, stream>>>(xn, xg1o, part, Wnb, bias, out);
    else
        gconv_mfma<<<512, 256, 0, stream>>>(x, xg1o, part, Wpb, bias, E, out);
}

// Round 3
// 271.433 us; speedup vs baseline: 1.0771x; 1.0180x over previous
//
#include <hip/hip_runtime.h>

// AVWGCN: B=32, N=2048, C=64, O=64, K=3, D=16
// R16 changes vs R15 (preamble now the longest dispatch: 45.6us at 26% HBM, 9% VALU,
// 39% occupancy -> one-shot block churn, not BW; BW floor is 15us for its 96MB):
//  - preamble: adj+saw bf16 conversion merged into ONE grid-strided segment
//    (1536 blocks x 8 batched float4/thread, all loads issued before converts) ->
//    grid drops 13648 -> 2896 blocks; long-lived blocks amortize dispatch churn
//    and keep 8 loads/thread in flight.
//  - reduce_z: 4096 one-shot blocks -> 1024 blocks x 4 unrolled grid-stride iters.
// gemm_bt256 unchanged from R15 (counted-vmcnt pipeline; dropped out of top-5).

typedef unsigned short u16;
typedef float f32x4 __attribute__((ext_vector_type(4)));
typedef __bf16 bf16x8 __attribute__((ext_vector_type(8)));
typedef unsigned short u16x8 __attribute__((ext_vector_type(8)));

#define PSTRIDE ((size_t)2048 * 2048)

__device__ __forceinline__ u16 f2bf(float f) {
    unsigned u = __float_as_uint(f);
    u += 0x7FFFu + ((u >> 16) & 1u);   // RNE
    return (u16)(u >> 16);
}
__device__ __forceinline__ float bf2f(u16 h) {
    return __uint_as_float((unsigned)h << 16);
}
__device__ __forceinline__ void gl_lds16(const void* g, void* l) {
    __builtin_amdgcn_global_load_lds(
        (const __attribute__((address_space(1))) unsigned*)g,
        (__attribute__((address_space(3))) unsigned*)l, 16, 0, 0);
}

// ---------------------------------------------------------------- preamble (fused)
// grid 2896: [0,256) z-gen | [256,1792) adj+saw bf16 grid-stride | [1792,2816) x-T
//            | [2816,2832) Wp | [2832,2896) bias
__global__ __launch_bounds__(256)
void preamble(const float* __restrict__ E, const float* __restrict__ adj,
              const float* __restrict__ saw, const float* __restrict__ x,
              const float* __restrict__ Wp, const float* __restrict__ bp,
              float* __restrict__ zf, u16* __restrict__ Acat,
              u16* __restrict__ sawb, u16* __restrict__ xtT,
              u16* __restrict__ Wpb, float* __restrict__ Wpbf,
              float* __restrict__ bias, u16* __restrict__ xn, int mode) {
    __shared__ u16 t[64][65];
    __shared__ float Bp[1024];
    const int bid = blockIdx.x, tid = threadIdx.x;

    if (bid < 256) {
        const int c0 = (bid & 31) * 64, r0 = (bid >> 5) * 256;
        const int r = r0 + tid;
        const float4* Er = (const float4*)(E + (size_t)r * 16);
        float4 e0 = Er[0], e1 = Er[1], e2 = Er[2], e3 = Er[3];
        *(float4*)(Bp + tid * 4) = *(const float4*)(E + (size_t)c0 * 16 + tid * 4);
        __syncthreads();
        float* zr = zf + (size_t)r * 2048 + c0;
#pragma unroll
        for (int cc = 0; cc < 4; ++cc) {
            float acc[16];
#pragma unroll
            for (int c = 0; c < 16; ++c) {
                const float* bp2 = Bp + (cc * 16 + c) * 16;
                float s = 0.f;
                s = fmaf(e0.x, bp2[0], s);  s = fmaf(e0.y, bp2[1], s);
                s = fmaf(e0.z, bp2[2], s);  s = fmaf(e0.w, bp2[3], s);
                s = fmaf(e1.x, bp2[4], s);  s = fmaf(e1.y, bp2[5], s);
                s = fmaf(e1.z, bp2[6], s);  s = fmaf(e1.w, bp2[7], s);
                s = fmaf(e2.x, bp2[8], s);  s = fmaf(e2.y, bp2[9], s);
                s = fmaf(e2.z, bp2[10], s); s = fmaf(e2.w, bp2[11], s);
                s = fmaf(e3.x, bp2[12], s); s = fmaf(e3.y, bp2[13], s);
                s = fmaf(e3.z, bp2[14], s); s = fmaf(e3.w, bp2[15], s);
                acc[c] = fmaxf(s, 0.f);
            }
#pragma unroll
            for (int q = 0; q < 4; ++q)
                *(float4*)(zr + cc * 16 + q * 4) =
                    make_float4(acc[q * 4], acc[q * 4 + 1], acc[q * 4 + 2], acc[q * 4 + 3]);
        }
    } else if (bid < 1792) {
        // adj (1,048,576 float4) + saw (2,097,152 float4) -> bf16, batched grid-stride
        const size_t NADJ = 1048576, STRIDE = (size_t)1536 * 256;
        const size_t e0 = (size_t)(bid - 256) * 256 + tid;
        float4 v[8];
#pragma unroll
        for (int it = 0; it < 8; ++it) {
            size_t idx = e0 + (size_t)it * STRIDE;
            const float* src = (idx < NADJ) ? (adj + idx * 4) : (saw + (idx - NADJ) * 4);
            v[it] = *(const float4*)src;
        }
#pragma unroll
        for (int it = 0; it < 8; ++it) {
            size_t idx = e0 + (size_t)it * STRIDE;
            ushort4 o = make_ushort4(f2bf(v[it].x), f2bf(v[it].y), f2bf(v[it].z), f2bf(v[it].w));
            if (idx < NADJ) {
                size_t j = idx * 4;
                int n = (int)(j >> 11), c = (int)(j & 2047);
                *(ushort4*)(Acat + (size_t)n * 4096 + 2048 + c) = o;
            } else {
                *(ushort4*)(sawb + (idx - NADJ) * 4) = o;
            }
        }
    } else if (bid < 2816) {
        int local = bid - 1792;
        int m0 = (local & 31) * 64, b = local >> 5;
        int c = tid & 63, g = tid >> 6;
#pragma unroll
        for (int r = 0; r < 16; ++r) {
            int mm = g * 16 + r;
            t[mm][c] = f2bf(x[((size_t)b * 2048 + m0 + mm) * 64 + c]);
        }
        __syncthreads();
#pragma unroll
        for (int r = 0; r < 16; ++r) {
            int cc = g * 16 + r;
            xtT[((size_t)b * 64 + cc) * 2048 + m0 + c] = t[c][cc];
        }
        if (mode) {
#pragma unroll
            for (int r = 0; r < 16; ++r) {
                int mm = g * 16 + r;
                xn[((size_t)(m0 + mm)) * 2048 + b * 64 + c] = t[mm][c];
            }
        }
    } else {
        int local = bid - 2816;
        if (local < 16) {
            const int d = local;
            const float* base = Wp + (size_t)d * 12288;    // [k][i][o]
            for (int idx = tid; idx < 12288; idx += 256) {
                int o = idx / 192, ki = idx - o * 192;
                int k = ki >> 6, i = ki & 63;
                float v;
                if (k == 0)      v = base[i * 64 + o] - base[2 * 4096 + i * 64 + o];
                else if (k == 1) v = base[4096 + i * 64 + o];
                else             v = 2.f * base[2 * 4096 + i * 64 + o];
                size_t dst = (size_t)(d * 64 + o) * 192 + ki;
                Wpb[dst] = f2bf(v);
                Wpbf[dst] = v;
            }
        } else {
            const int nb = local - 16;
#pragma unroll
            for (int it = 0; it < 8; ++it) {
                int idx = tid + it * 256;
                int n = nb * 32 + (idx >> 6), o = idx & 63;
                float s = 0.f;
#pragma unroll
                for (int d = 0; d < 16; ++d) s = fmaf(E[n * 16 + d], bp[d * 64 + o], s);
                bias[(size_t)n * 64 + o] = s;
            }
        }
    }
}

// ---------------------------------------------------------------- mid: softmax + wgen
__global__ __launch_bounds__(256)
void mid(const float* __restrict__ zf, u16* __restrict__ Acat,
         const float* __restrict__ E, const float* __restrict__ Wpbf,
         u16* __restrict__ Wnb) {
    __shared__ float red[4];
    __shared__ float Es[32 * 16];
    const int bid = blockIdx.x, tid = threadIdx.x;
    if (bid < 2048) {
        const int n = bid, lane = tid & 63, wave = tid >> 6;
        const float* zr = zf + (size_t)n * 2048;
        float4 a = *(const float4*)(zr + tid * 8);
        float4 b = *(const float4*)(zr + tid * 8 + 4);
        float mx = fmaxf(fmaxf(fmaxf(a.x, a.y), fmaxf(a.z, a.w)),
                         fmaxf(fmaxf(b.x, b.y), fmaxf(b.z, b.w)));
        for (int off = 32; off; off >>= 1) mx = fmaxf(mx, __shfl_down(mx, off, 64));
        if (lane == 0) red[wave] = mx;
        __syncthreads();
        mx = fmaxf(fmaxf(red[0], red[1]), fmaxf(red[2], red[3]));
        __syncthreads();
        float v[8] = {__expf(a.x - mx), __expf(a.y - mx), __expf(a.z - mx), __expf(a.w - mx),
                      __expf(b.x - mx), __expf(b.y - mx), __expf(b.z - mx), __expf(b.w - mx)};
        float sum = v[0] + v[1] + v[2] + v[3] + v[4] + v[5] + v[6] + v[7];
        for (int off = 32; off; off >>= 1) sum += __shfl_down(sum, off, 64);
        if (lane == 0) red[wave] = sum;
        __syncthreads();
        sum = red[0] + red[1] + red[2] + red[3];
        float inv = 1.f / sum;
        u16* orow = Acat + (size_t)n * 4096 + tid * 8;
        *(ushort4*)orow = make_ushort4(f2bf(v[0] * inv), f2bf(v[1] * inv),
                                       f2bf(v[2] * inv), f2bf(v[3] * inv));
        *(ushort4*)(orow + 4) = make_ushort4(f2bf(v[4] * inv), f2bf(v[5] * inv),
                                             f2bf(v[6] * inv), f2bf(v[7] * inv));
    } else {
        const int w = bid - 2048;
        const int c0 = (w % 12) * 1024, n0 = (w / 12) * 32;
        for (int j = tid; j < 512; j += 256) Es[j] = E[(size_t)n0 * 16 + j];
        float4 wf[16];
#pragma unroll
        for (int d = 0; d < 16; ++d)
            wf[d] = *(const float4*)(Wpbf + (size_t)d * 12288 + c0 + tid * 4);
        __syncthreads();
        for (int nl = 0; nl < 32; ++nl) {
            float4 s = make_float4(0.f, 0.f, 0.f, 0.f);
#pragma unroll
            for (int d = 0; d < 16; ++d) {
                float e = Es[nl * 16 + d];
                s.x = fmaf(e, wf[d].x, s.x);
                s.y = fmaf(e, wf[d].y, s.y);
                s.z = fmaf(e, wf[d].z, s.z);
                s.w = fmaf(e, wf[d].w, s.w);
            }
            *(ushort4*)(Wnb + (size_t)(n0 + nl) * 12288 + c0 + tid * 4) =
                make_ushort4(f2bf(s.x), f2bf(s.y), f2bf(s.z), f2bf(s.w));
        }
    }
}

// ---------------------------------------------------------------- GEMM 256x256, BK=64, split-K
// 8 waves (2Mx4N), dbuf LDS (128KB), gl_lds staging spread 2 chunks/phase, counted vmcnt
// (never 0 in main loop), 4 quadrant-phases per K-tile, raw s_barrier + setprio.
__global__ __launch_bounds__(512, 2)
void gemm_bt256(const u16* __restrict__ A, const u16* __restrict__ Bt,
                u16* __restrict__ Cp, int M, int N, int K, int Kh) {
    __shared__ alignas(16) u16 As[2][256 * 64];
    __shared__ alignas(16) u16 Bs[2][256 * 64];
    const int tid = threadIdx.x, lane = tid & 63, wave = tid >> 6;

    // bijective XCD swizzle of the linearized block id (nwg % 8 == 0 here)
    const int nbx = gridDim.x, nby = gridDim.y, nbz = gridDim.z;
    const int nwg = nbx * nby * nbz;
    int lin = (blockIdx.z * nby + blockIdx.y) * nbx + blockIdx.x;
    if ((nwg & 7) == 0) lin = (lin & 7) * (nwg >> 3) + (lin >> 3);
    const int bz = lin / (nbx * nby);
    const int r2 = lin - bz * nbx * nby;
    const int by = r2 / nbx, bx = r2 - by * nbx;

    const int m0 = by * 256, n0 = bx * 256;
    const int kbeg = bz * Kh;
    const int NT = Kh >> 6;
    const int wm = (wave >> 2) * 128, wn = (wave & 3) * 64;
    const int ml = lane & 15, c0l = lane >> 4;

    // staging geometry: chunk r covers rows [64r, 64r+64) of the 256-row tile;
    // linear LDS dest (slot s -> 16B), pre-swizzled global source column.
    int sI[4], rowI[4], gcI[4];
#pragma unroll
    for (int r = 0; r < 4; ++r) {
        int s = r * 512 + tid;
        sI[r] = s; rowI[r] = s >> 3; gcI[r] = (s & 7) ^ ((s >> 3) & 7);
    }

    f32x4 acc[8][4] = {};
    bf16x8 af[4][2], bv[2][2];

// staging macros: chunk r of tile with K-offset kt into buffer buf
#define LOADA(r_, kt_, buf_) \
    gl_lds16(A + (size_t)(m0 + rowI[r_]) * K + (kt_) + gcI[r_] * 8, \
             &As[buf_][sI[r_] * 8])
#define LOADB(r_, kt_, buf_) \
    gl_lds16(Bt + (size_t)(n0 + rowI[r_]) * K + (kt_) + gcI[r_] * 8, \
             &Bs[buf_][sI[r_] * 8])

// ds-read macros: A-quarter qa (64 rows of the wave's 128-row strip),
// B-eighth qb (32 cols of the wave's 64-col strip)
#define DSRA(qa_) \
    _Pragma("unroll") \
    for (int i = 0; i < 4; ++i) { \
        const int mr = wm + (qa_) * 64 + i * 16 + ml; \
        _Pragma("unroll") \
        for (int ks = 0; ks < 2; ++ks) \
            af[i][ks] = *(const bf16x8*)(Asc + mr * 64 + (((c0l + ks * 4) ^ (mr & 7)) * 8)); \
    }
#define DSRB(qb_) \
    _Pragma("unroll") \
    for (int j = 0; j < 2; ++j) { \
        const int nr = wn + (qb_) * 32 + j * 16 + ml; \
        _Pragma("unroll") \
        for (int ks = 0; ks < 2; ++ks) \
            bv[j][ks] = *(const bf16x8*)(Bsc + nr * 64 + (((c0l + ks * 4) ^ (nr & 7)) * 8)); \
    }
// MFMA cluster for C-quadrant (io, jo)
#define MMQ(io_, jo_) \
    __builtin_amdgcn_s_barrier(); \
    asm volatile("s_waitcnt lgkmcnt(0)" ::: "memory"); \
    __builtin_amdgcn_s_setprio(1); \
    _Pragma("unroll") \
    for (int ks = 0; ks < 2; ++ks) \
        _Pragma("unroll") \
        for (int i = 0; i < 4; ++i) \
            _Pragma("unroll") \
            for (int j = 0; j < 2; ++j) \
                acc[(io_) + i][(jo_) + j] = __builtin_amdgcn_mfma_f32_16x16x32_bf16( \
                    af[i][ks], bv[j][ks], acc[(io_) + i][(jo_) + j], 0, 0, 0); \
    __builtin_amdgcn_s_setprio(0);

    // prologue: stage tile 0 into buf 0, drain once
#pragma unroll
    for (int r = 0; r < 4; ++r) LOADA(r, kbeg, 0);
#pragma unroll
    for (int r = 0; r < 4; ++r) LOADB(r, kbeg, 0);
    asm volatile("s_waitcnt vmcnt(0)" ::: "memory");
    __builtin_amdgcn_s_barrier();

    // main loop: tiles 0..NT-2, each issues tile t+1 spread across its 4 phases
    for (int t = 0; t < NT - 1; ++t) {
        const int cur = t & 1, nxt = cur ^ 1;
        const u16* Asc = As[cur];
        const u16* Bsc = Bs[cur];
        const int k1 = kbeg + (t + 1) * 64;

        // ph0: quad (0,0)
        DSRA(0); DSRB(0);
        LOADB(0, k1, nxt); LOADB(1, k1, nxt);
        MMQ(0, 0);
        __builtin_amdgcn_s_barrier();

        // ph1: quad (0,1); end-wait: A1,A3(t) landed (4 B-chunks stay in flight)
        DSRB(1);
        LOADB(2, k1, nxt); LOADB(3, k1, nxt);
        MMQ(0, 2);
        asm volatile("s_waitcnt vmcnt(4)" ::: "memory");
        __builtin_amdgcn_s_barrier();

        // ph2: quad (1,1)
        DSRA(1);
        LOADA(0, k1, nxt); LOADA(2, k1, nxt);
        MMQ(4, 2);
        __builtin_amdgcn_s_barrier();

        // ph3: quad (1,0); end-wait: B(t+1)+A0,A2(t+1) landed (A1,A3(t+1) in flight)
        DSRB(0);
        LOADA(1, k1, nxt); LOADA(3, k1, nxt);
        MMQ(4, 0);
        asm volatile("s_waitcnt vmcnt(2)" ::: "memory");
        __builtin_amdgcn_s_barrier();
    }

    // peeled last tile: no staging; vmcnt(0) before ph2's consumers (A1,A3 of this tile)
    {
        const int cur = (NT - 1) & 1;
        const u16* Asc = As[cur];
        const u16* Bsc = Bs[cur];

        DSRA(0); DSRB(0);
        MMQ(0, 0);
        __builtin_amdgcn_s_barrier();

        DSRB(1);
        MMQ(0, 2);
        asm volatile("s_waitcnt vmcnt(0)" ::: "memory");
        __builtin_amdgcn_s_barrier();

        DSRA(1);
        MMQ(4, 2);
        __builtin_amdgcn_s_barrier();

        DSRB(0);
        MMQ(4, 0);
    }

#undef LOADA
#undef LOADB
#undef DSRA
#undef DSRB
#undef MMQ

    const int col_l = lane & 15, rl = (lane >> 4) * 4;
    u16* Cz = Cp + (size_t)bz * M * N;
#pragma unroll
    for (int i = 0; i < 8; ++i)
#pragma unroll
        for (int j = 0; j < 4; ++j)
#pragma unroll
            for (int r = 0; r < 4; ++r) {
                int row = m0 + wm + i * 16 + rl + r;
                int col = n0 + wn + j * 16 + col_l;
                Cz[(size_t)row * N + col] = f2bf(acc[i][j][r]);
            }
}

// ---------------------------------------------------------------- reduce_z
// grid-stride: 1024 blocks x 4 iterations (was 4096 one-shot blocks)
__global__ __launch_bounds__(256)
void reduce_z(const u16* __restrict__ p, const u16* __restrict__ Acat,
              u16* __restrict__ S) {
    const size_t base = ((size_t)blockIdx.x * 256 + threadIdx.x) * 4;
    const size_t STRIDE = (size_t)1024 * 256 * 4;
#pragma unroll
    for (int it = 0; it < 4; ++it) {
        size_t j = base + (size_t)it * STRIDE;
        ushort4 p0 = *(const ushort4*)(p + j);
        ushort4 p1 = *(const ushort4*)(p + PSTRIDE + j);
        ushort4 p2 = *(const ushort4*)(p + 2 * PSTRIDE + j);
        ushort4 p3 = *(const ushort4*)(p + 3 * PSTRIDE + j);
        int row = (int)(j >> 11), col = (int)(j & 2047);
        ushort4 sp = *(const ushort4*)(Acat + (size_t)row * 4096 + col);
        ushort4 ad = *(const ushort4*)(Acat + (size_t)row * 4096 + 2048 + col);
        float z0 = bf2f(p0.x) + bf2f(p1.x) + bf2f(p2.x) + bf2f(p3.x);
        float z1 = bf2f(p0.y) + bf2f(p1.y) + bf2f(p2.y) + bf2f(p3.y);
        float z2 = bf2f(p0.z) + bf2f(p1.z) + bf2f(p2.z) + bf2f(p3.z);
        float z3 = bf2f(p0.w) + bf2f(p1.w) + bf2f(p2.w) + bf2f(p3.w);
        float s0 = 1.f / (1.f + __expf(-z0)), s1 = 1.f / (1.f + __expf(-z1));
        float s2 = 1.f / (1.f + __expf(-z2)), s3 = 1.f / (1.f + __expf(-z3));
        ushort4 o = make_ushort4(
            f2bf(s0 * bf2f(ad.x) + (1.f - s0) * bf2f(sp.x)),
            f2bf(s1 * bf2f(ad.y) + (1.f - s1) * bf2f(sp.y)),
            f2bf(s2 * bf2f(ad.z) + (1.f - s2) * bf2f(sp.z)),
            f2bf(s3 * bf2f(ad.w) + (1.f - s3) * bf2f(sp.w)));
        *(ushort4*)(S + j) = o;
    }
}

// ---------------------------------------------------------------- reduceT
__global__ __launch_bounds__(256)
void reduceT(const u16* __restrict__ p, u16* __restrict__ xg1o,
             u16* __restrict__ xg1T, int mode) {
    __shared__ u16 t[64][68];
    int bx = blockIdx.x * 64, by = blockIdx.y * 64;
    int cg = threadIdx.x & 15, rg = threadIdx.x >> 4;
    int b = bx >> 6;
#pragma unroll
    for (int rr = 0; rr < 4; ++rr) {
        int row = rg * 4 + rr;
        size_t idx = (size_t)(by + row) * 2048 + bx + cg * 4;
        ushort4 q0 = *(const ushort4*)(p + idx);
        ushort4 q1 = *(const ushort4*)(p + PSTRIDE + idx);
        ushort4 q2 = *(const ushort4*)(p + 2 * PSTRIDE + idx);
        ushort4 q3 = *(const ushort4*)(p + 3 * PSTRIDE + idx);
        ushort4 v = make_ushort4(
            f2bf(bf2f(q0.x) + bf2f(q1.x) + bf2f(q2.x) + bf2f(q3.x)),
            f2bf(bf2f(q0.y) + bf2f(q1.y) + bf2f(q2.y) + bf2f(q3.y)),
            f2bf(bf2f(q0.z) + bf2f(q1.z) + bf2f(q2.z) + bf2f(q3.z)),
            f2bf(bf2f(q0.w) + bf2f(q1.w) + bf2f(q2.w) + bf2f(q3.w)));
        if (mode) *(ushort4*)(xg1o + idx) = v;
        else      *(ushort4*)(xg1o + ((size_t)b * 2048 + by + row) * 64 + cg * 4) = v;
        *(ushort4*)(&t[row][cg * 4]) = v;
    }
    __syncthreads();
    int c = threadIdx.x & 63, g = threadIdx.x >> 6;
#pragma unroll
    for (int r = 0; r < 16; ++r) {
        int row = g * 16 + r;
        xg1T[(size_t)(bx + row) * 2048 + by + c] = t[c][row];
    }
}

// ---------------------------------------------------------------- gconv_wn (Wn mode)
__global__ __launch_bounds__(256, 4)
void gconv_wn(const u16* __restrict__ xn, const u16* __restrict__ xg1n,
              const u16* __restrict__ p, const u16* __restrict__ Wnb,
              const float* __restrict__ bias, float* __restrict__ out) {
    __shared__ alignas(16) u16 As[32 * 192];
    __shared__ alignas(16) u16 Bs[64 * 192];
    const int n = blockIdx.x, tid = threadIdx.x;
    const int lane = tid & 63, wave = tid >> 6;
    const int wn2 = wave * 16;
    const int ml = lane & 15, c0l = lane >> 4;
    const int col = lane & 15, rl = (lane >> 4) * 4;

#pragma unroll
    for (int it = 0; it < 6; ++it) {
        int s = tid + it * 256;
        int row = s / 24, sc = s - row * 24;
        int gc = (sc & 24) | ((sc ^ row) & 7);
        gl_lds16(Wnb + (size_t)n * 12288 + (size_t)row * 192 + gc * 8, Bs + (size_t)s * 8);
    }
#pragma unroll
    for (int it = 0; it < 3; ++it) {
        int s = tid + it * 256;
        int row = s / 24, sc = s - row * 24;
        int gc = (sc & 24) | ((sc ^ row) & 7);
        u16x8 v;
        if (gc < 8) {
            v = *(const u16x8*)(xn + (size_t)n * 2048 + row * 64 + (gc & 7) * 8);
        } else if (gc < 16) {
            v = *(const u16x8*)(xg1n + (size_t)n * 2048 + row * 64 + (gc & 7) * 8);
        } else {
            const u16* pp = p + (size_t)n * 2048 + row * 64 + (gc & 7) * 8;
            u16x8 q0 = *(const u16x8*)pp;
            u16x8 q1 = *(const u16x8*)(pp + PSTRIDE);
            u16x8 q2 = *(const u16x8*)(pp + 2 * PSTRIDE);
            u16x8 q3 = *(const u16x8*)(pp + 3 * PSTRIDE);
#pragma unroll
            for (int tt = 0; tt < 8; ++tt)
                v[tt] = f2bf(bf2f(q0[tt]) + bf2f(q1[tt]) + bf2f(q2[tt]) + bf2f(q3[tt]));
        }
        *(u16x8*)(As + (size_t)s * 8) = v;
    }
    float bv0 = bias[(size_t)n * 64 + wn2 + col];
    f32x4 acc[2];
#pragma unroll
    for (int mt = 0; mt < 2; ++mt)
#pragma unroll
        for (int r = 0; r < 4; ++r) acc[mt][r] = bv0;
    __syncthreads();

#pragma unroll
    for (int ks = 0; ks < 6; ++ks) {
        int c = c0l + ks * 4;
        int o = wn2 + ml;
        bf16x8 bfrag = *(const bf16x8*)(Bs + (o * 24 + ((c & 24) | ((c ^ (o & 7)) & 7))) * 8);
#pragma unroll
        for (int mt = 0; mt < 2; ++mt) {
            int m = mt * 16 + ml;
            bf16x8 afrag = *(const bf16x8*)(As + (m * 24 + ((c & 24) | ((c ^ (m & 7)) & 7))) * 8);
            acc[mt] = __builtin_amdgcn_mfma_f32_16x16x32_bf16(afrag, bfrag, acc[mt], 0, 0, 0);
        }
    }
#pragma unroll
    for (int mt = 0; mt < 2; ++mt)
#pragma unroll
        for (int r = 0; r < 4; ++r) {
            int b = mt * 16 + rl + r;
            out[((size_t)b * 2048 + n) * 64 + wn2 + col] = acc[mt][r];
        }
}

// ---------------------------------------------------------------- gconv_mfma (legacy fallback)
__global__ __launch_bounds__(256, 2)
void gconv_mfma(const float* __restrict__ x, const u16* __restrict__ xg1,
                const u16* __restrict__ p, const u16* __restrict__ Wpb,
                const float* __restrict__ bias, const float* __restrict__ E,
                float* __restrict__ out) {
    __shared__ alignas(16) float El[16 * 128];
    const int tid = threadIdx.x, lane = tid & 63, wave = tid >> 6;
    const int m0 = blockIdx.x * 128, nb = m0 & 2047, bB = m0 >> 11;
    const int wm = (wave >> 1) * 64, wn = (wave & 1) * 32;
    const int ml = lane & 15, c0l = lane >> 4;
    const int col_l = lane & 15, rl = (lane >> 4) * 4;

#pragma unroll
    for (int it = 0; it < 8; ++it) {
        int idx = tid + it * 256;
        El[idx] = E[(size_t)(nb + (idx & 127)) * 16 + (idx >> 7)];
    }
    __syncthreads();

    bf16x8 af[4][6];
#pragma unroll
    for (int i = 0; i < 4; ++i) {
        const int row = m0 + wm + i * 16 + ml;
        const int n = row & 2047;
#pragma unroll
        for (int ks = 0; ks < 2; ++ks) {
            const float* xp = x + (size_t)row * 64 + (c0l + ks * 4) * 8;
            float4 a = *(const float4*)xp, b4 = *(const float4*)(xp + 4);
            u16x8 v;
            v[0] = f2bf(a.x);  v[1] = f2bf(a.y);  v[2] = f2bf(a.z);  v[3] = f2bf(a.w);
            v[4] = f2bf(b4.x); v[5] = f2bf(b4.y); v[6] = f2bf(b4.z); v[7] = f2bf(b4.w);
            af[i][ks] = __builtin_bit_cast(bf16x8, v);
        }
#pragma unroll
        for (int ks = 2; ks < 4; ++ks)
            af[i][ks] = *(const bf16x8*)(xg1 + (size_t)row * 64 + (c0l + ks * 4 - 8) * 8);
#pragma unroll
        for (int ks = 4; ks < 6; ++ks) {
            const u16* pp = p + (size_t)n * 2048 + bB * 64 + (c0l + ks * 4 - 16) * 8;
            u16x8 q0 = *(const u16x8*)pp;
            u16x8 q1 = *(const u16x8*)(pp + PSTRIDE);
            u16x8 q2 = *(const u16x8*)(pp + 2 * PSTRIDE);
            u16x8 q3 = *(const u16x8*)(pp + 3 * PSTRIDE);
            u16x8 v;
#pragma unroll
            for (int tt = 0; tt < 8; ++tt)
                v[tt] = f2bf(bf2f(q0[tt]) + bf2f(q1[tt]) + bf2f(q2[tt]) + bf2f(q3[tt]));
            af[i][ks] = __builtin_bit_cast(bf16x8, v);
        }
    }

    f32x4 oacc[4][2];
#pragma unroll
    for (int i = 0; i < 4; ++i)
#pragma unroll
        for (int j = 0; j < 2; ++j)
#pragma unroll
            for (int r = 0; r < 4; ++r)
                oacc[i][j][r] = bias[(size_t)(nb + wm + i * 16 + rl + r) * 64 + wn + j * 16 + col_l];

#pragma unroll 2
    for (int d = 0; d < 16; ++d) {
        bf16x8 bv[2][6];
#pragma unroll
        for (int j = 0; j < 2; ++j) {
            const u16* wp = Wpb + (size_t)(d * 64 + wn + j * 16 + ml) * 192 + c0l * 8;
#pragma unroll
            for (int ks = 0; ks < 6; ++ks)
                bv[j][ks] = *(const bf16x8*)(wp + ks * 32);
        }
        f32x4 tmp[4][2] = {};
#pragma unroll
        for (int ks = 0; ks < 6; ++ks)
#pragma unroll
            for (int i = 0; i < 4; ++i)
#pragma unroll
                for (int j = 0; j < 2; ++j)
                    tmp[i][j] = __builtin_amdgcn_mfma_f32_16x16x32_bf16(af[i][ks], bv[j][ks], tmp[i][j], 0, 0, 0);
#pragma unroll
        for (int i = 0; i < 4; ++i) {
            f32x4 ev = *(const f32x4*)(El + d * 128 + wm + i * 16 + rl);
#pragma unroll
            for (int r = 0; r < 4; ++r)
#pragma unroll
                for (int j = 0; j < 2; ++j)
                    oacc[i][j][r] = fmaf(ev[r], tmp[i][j][r], oacc[i][j][r]);
        }
    }
#pragma unroll
    for (int i = 0; i < 4; ++i)
#pragma unroll
        for (int j = 0; j < 2; ++j)
#pragma unroll
            for (int r = 0; r < 4; ++r)
                out[(size_t)(m0 + wm + i * 16 + rl + r) * 64 + wn + j * 16 + col_l] = oacc[i][j][r];
}

// ---------------------------------------------------------------- launch
extern "C" void kernel_launch(void* const* d_in, const int* in_sizes, int n_in,
                              void* d_out, int out_size, void* d_ws, size_t ws_size,
                              hipStream_t stream) {
    const float* x   = (const float*)d_in[0];
    const float* E   = (const float*)d_in[1];
    const float* adj = (const float*)d_in[2];
    const float* Wp  = (const float*)d_in[3];
    const float* bp  = (const float*)d_in[4];
    const float* saw = (const float*)d_in[5];
    float* out = (float*)d_out;

    char* ws = (char*)d_ws;
    const size_t MB = 1u << 20;
    const int wn_mode = (ws_size >= 140 * MB) ? 1 : 0;

    u16*   Acat  = (u16*)(ws);                  // [0,16M)
    u16*   sawb  = (u16*)(ws + 16 * MB);        // [16,32M)
    u16*   XtT   = (u16*)(ws + 32 * MB);        // [32,40M)
    u16*   Wpb   = (u16*)(ws + 40 * MB);        // [40,40.4M) bf16
    float* bias  = (float*)(ws + 41 * MB);      // [41,41.5M)
    float* Wpbf  = (float*)(ws + 42 * MB);      // [42,42.8M) fp32
    float* zf    = (float*)(ws + 48 * MB);      // [48,64M)
    u16*   part  = (u16*)(ws + 48 * MB);        // [48,80M)
    u16*   S_bf  = (u16*)(ws + 16 * MB);        // [16,24M)
    u16*   xg1T  = (u16*)(ws + 24 * MB);        // [24,32M)
    u16*   xg1o  = (u16*)(ws);                  // [0,8M)
    u16*   xn    = (u16*)(ws + 80 * MB);        // [80,88M)   wn only
    u16*   Wnb   = (u16*)(ws + 88 * MB);        // [88,138.4M) wn only

    preamble<<<2896, 256, 0, stream>>>(E, adj, saw, x, Wp, bp, zf, Acat, sawb, XtT,
                                       Wpb, Wpbf, bias, xn, wn_mode);
    mid<<<wn_mode ? 2816 : 2048, 256, 0, stream>>>(zf, Acat, E, Wpbf, Wnb);

    gemm_bt256<<<dim3(8, 8, 4), 512, 0, stream>>>(Acat, sawb, part, 2048, 2048, 4096, 1024);
    reduce_z<<<1024, 256, 0, stream>>>(part, Acat, S_bf);
    gemm_bt256<<<dim3(8, 8, 4), 512, 0, stream>>>(S_bf, XtT, part, 2048, 2048, 2048, 512);
    reduceT<<<dim3(32, 32), 256, 0, stream>>>(part, xg1o, xg1T, wn_mode);
    gemm_bt256<<<dim3(8, 8, 4), 512, 0, stream>>>(S_bf, xg1T, part, 2048, 2048, 2048, 512);

    if (wn_mode)
        gconv_wn<<<2048, 256, 0, stream>>>(xn, xg1o, part, Wnb, bias, out);
    else
        gconv_mfma<<<512, 256, 0, stream>>>(x, xg1o, part, Wpb, bias, E, out);
}